// Round 8
// baseline (272.670 us; speedup 1.0000x reference)
//
#include <hip/hip_runtime.h>
#include <hip/hip_bf16.h>
#include <math.h>

// ---------------------------------------------------------------------------
// GraphConv GNN, round 7: fix R6's divergent-shfl bug in the gather tail.
// Padding lanes carry zero WEIGHT (shfl-safe masking); all shfls are
// unconditional with the full wave active.
// ---------------------------------------------------------------------------

typedef __attribute__((ext_vector_type(8))) short short8;
typedef __attribute__((ext_vector_type(4))) float f32x4;

static __device__ __forceinline__ float bf2f(unsigned short u) {
    return __uint_as_float(((unsigned)u) << 16);
}

// ---- CSR scan -------------------------------------------------------------
__global__ __launch_bounds__(256) void scan_block_sums(
    const int* __restrict__ counts, int* __restrict__ bsum, int n)
{
    __shared__ int sh[256];
    int idx = blockIdx.x * 256 + threadIdx.x;
    sh[threadIdx.x] = (idx < n) ? counts[idx] : 0;
    __syncthreads();
#pragma unroll
    for (int off = 128; off; off >>= 1) {
        if (threadIdx.x < off) sh[threadIdx.x] += sh[threadIdx.x + off];
        __syncthreads();
    }
    if (threadIdx.x == 0) bsum[blockIdx.x] = sh[0];
}

__global__ __launch_bounds__(256) void scan_bsum(
    const int* __restrict__ bsum, int* __restrict__ bpre, int nb)
{
    __shared__ int sh[256];
    int t = threadIdx.x;
    int v = (t < nb) ? bsum[t] : 0;
    sh[t] = v;
    __syncthreads();
#pragma unroll
    for (int off = 1; off < 256; off <<= 1) {
        int u = (t >= off) ? sh[t - off] : 0;
        __syncthreads();
        sh[t] += u;
        __syncthreads();
    }
    bpre[t] = sh[t] - v;   // exclusive
}

__global__ __launch_bounds__(256) void scan_final(
    const int* __restrict__ counts, const int* __restrict__ bpre,
    int* __restrict__ row_ptr, int* __restrict__ cursor, int n, int Etot)
{
    __shared__ int sh[256];
    int t = threadIdx.x;
    int idx = blockIdx.x * 256 + t;
    int v = (idx < n) ? counts[idx] : 0;
    sh[t] = v;
    __syncthreads();
#pragma unroll
    for (int off = 1; off < 256; off <<= 1) {
        int u = (t >= off) ? sh[t - off] : 0;
        __syncthreads();
        sh[t] += u;
        __syncthreads();
    }
    if (idx < n) {
        int val = bpre[blockIdx.x] + sh[t] - v;
        row_ptr[idx] = val;
        cursor[idx]  = val;
    }
    if (idx == 0) row_ptr[n] = Etot;
}

__global__ __launch_bounds__(256) void fill_kernel(
    const int* __restrict__ ei, const float* __restrict__ ew,
    int* __restrict__ cursor, int2* __restrict__ edges, int E)
{
    int e = blockIdx.x * 256 + threadIdx.x;
    if (e >= E) return;
    int d = ei[E + e];
    int p = atomicAdd(&cursor[d], 1);
    edges[p] = make_int2(ei[e], __float_as_int(ew[e]));
}

// ---- fused prep: count atomics + x->bf16 + weight transposes --------------
__global__ __launch_bounds__(256) void prep_all(
    const int* __restrict__ ei, int* __restrict__ counts, int E,
    const float* __restrict__ x, __hip_bfloat16* __restrict__ xb, int NX8,
    const float* __restrict__ w1_rel, const float* __restrict__ w1_root,
    const float* __restrict__ w2_rel, const float* __restrict__ w2_root,
    const float* __restrict__ w_lin,
    __hip_bfloat16* __restrict__ w1relT, __hip_bfloat16* __restrict__ w1rootT,
    __hip_bfloat16* __restrict__ w2relT, __hip_bfloat16* __restrict__ w2rootT,
    __hip_bfloat16* __restrict__ wlinT)
{
    int idx = blockIdx.x * 256 + threadIdx.x;
    if (idx < E) {
        atomicAdd(&counts[ei[E + idx]], 1);
        return;
    }
    idx -= E;
    if (idx < NX8) {   // x -> bf16, 8 elems/thread
        float4 a = *(const float4*)&x[(size_t)idx * 8];
        float4 b = *(const float4*)&x[(size_t)idx * 8 + 4];
        __hip_bfloat16 o[8] = {
            __float2bfloat16(a.x), __float2bfloat16(a.y),
            __float2bfloat16(a.z), __float2bfloat16(a.w),
            __float2bfloat16(b.x), __float2bfloat16(b.y),
            __float2bfloat16(b.z), __float2bfloat16(b.w) };
        *(short8*)&xb[(size_t)idx * 8] = *(short8*)o;
        return;
    }
    idx -= NX8;
    if (idx < 65536) {                       // w1_rel/w1_root [128,256] -> [256,128]
        const float* src = (idx < 32768) ? w1_rel : w1_root;
        __hip_bfloat16* dst = (idx < 32768) ? w1relT : w1rootT;
        int i = idx & 32767;
        int k = i >> 8, c = i & 255;
        dst[c * 128 + k] = __float2bfloat16(src[i]);
    } else if (idx < 196608) {               // w2_rel/w2_root [256,256]^T
        int j = idx - 65536;
        const float* src = (j < 65536) ? w2_rel : w2_root;
        __hip_bfloat16* dst = (j < 65536) ? w2relT : w2rootT;
        int i = j & 65535;
        int k = i >> 8, c = i & 255;
        dst[c * 256 + k] = __float2bfloat16(src[i]);
    } else if (idx < 229376) {               // w_lin [512,40] -> [2][64][256]
        int i = idx - 196608;
        int seg = i >> 14, c = (i >> 8) & 63, k = i & 255;
        float v = (c < 40) ? w_lin[(size_t)(seg * 256 + k) * 40 + c] : 0.f;
        wlinT[i] = __float2bfloat16(v);
    }
}

// ---- gather: agg[v,:] = sum_e w_e * feat[src_e,:]  (bf16, fp32 acc) -------
// One wave per node. Edge (src,w) pairs loaded once per 64-edge chunk into a
// register (coalesced); padding lanes carry weight 0 so every __shfl is
// unconditional with all 64 lanes active. Feature-row loads have no
// global-load dependence -> 4 independent row loads in flight per wave.
template <int C>
__global__ __launch_bounds__(256) void gather_bf16(
    const __hip_bfloat16* __restrict__ feat,
    const int2* __restrict__ edges,
    const int*  __restrict__ rp,
    __hip_bfloat16* __restrict__ agg, int n)
{
    const int node = (blockIdx.x * 256 + threadIdx.x) >> 6;
    const int lane = threadIdx.x & 63;
    if (node >= n) return;
    const int beg = __builtin_amdgcn_readfirstlane(rp[node]);
    const int end = __builtin_amdgcn_readfirstlane(rp[node + 1]);

    constexpr int EPW = (C == 128) ? 4 : 2;      // edge slots per wave-step
    const int es = (C == 128) ? (lane >> 4) : (lane >> 5);
    const int ch = (C == 128) ? (lane & 15) : (lane & 31);

    const unsigned short* fb = (const unsigned short*)feat;
    const unsigned coff = (unsigned)ch * 8;      // element offset of 16B chunk

    float acc[8] = {};

    for (int base = beg; base < end; base += 64) {
        const int m = min(64, end - base);       // edges in this chunk
        // one coalesced edge load; padding lanes get weight 0 (shfl-safe mask)
        int2 ev = edges[base + ((lane < m) ? lane : (m - 1))];
        if (lane >= m) ev.y = 0;

        int s = 0;
        // main: 4*EPW edges/iter, only reads lanes < m (all true edges)
        for (; s + 4 * EPW <= m; s += 4 * EPW) {
            int j0 = s + es, j1 = j0 + EPW, j2 = j1 + EPW, j3 = j2 + EPW;
            int   s0 = __shfl(ev.x, j0, 64), s1 = __shfl(ev.x, j1, 64);
            int   s2 = __shfl(ev.x, j2, 64), s3 = __shfl(ev.x, j3, 64);
            float w0 = __int_as_float(__shfl(ev.y, j0, 64));
            float w1 = __int_as_float(__shfl(ev.y, j1, 64));
            float w2 = __int_as_float(__shfl(ev.y, j2, 64));
            float w3 = __int_as_float(__shfl(ev.y, j3, 64));
            short8 u0 = *(const short8*)(fb + (unsigned)s0 * C + coff);
            short8 u1 = *(const short8*)(fb + (unsigned)s1 * C + coff);
            short8 u2 = *(const short8*)(fb + (unsigned)s2 * C + coff);
            short8 u3 = *(const short8*)(fb + (unsigned)s3 * C + coff);
#pragma unroll
            for (int k = 0; k < 8; ++k) {
                float a = fmaf(bf2f((unsigned short)u0[k]), w0,
                               bf2f((unsigned short)u1[k]) * w1);
                float b = fmaf(bf2f((unsigned short)u2[k]), w2,
                               bf2f((unsigned short)u3[k]) * w3);
                acc[k] += a + b;
            }
        }
        // tail: clamped index lands on a zero-weight pad lane -> contributes 0
        for (; s < m; s += EPW) {
            int j = min(s + es, 63);
            int   sj = __shfl(ev.x, j, 64);
            float wj = __int_as_float(__shfl(ev.y, j, 64));
            short8 u = *(const short8*)(fb + (unsigned)sj * C + coff);
#pragma unroll
            for (int k = 0; k < 8; ++k)
                acc[k] = fmaf(bf2f((unsigned short)u[k]), wj, acc[k]);
        }
    }

    // fold edge slots
#pragma unroll
    for (int k = 0; k < 8; ++k) {
        if constexpr (C == 128) {
            acc[k] += __shfl_xor(acc[k], 16, 64);
            acc[k] += __shfl_xor(acc[k], 32, 64);
        } else {
            acc[k] += __shfl_xor(acc[k], 32, 64);
        }
    }
    if (es == 0) {
        __hip_bfloat16 o[8];
#pragma unroll
        for (int k = 0; k < 8; ++k) o[k] = __float2bfloat16(acc[k]);
        *(short8*)(agg + (size_t)node * C + coff) = *(short8*)o;
    }
}

// ---- MFMA GEMM: C = relu(A0@W0 + A1@W1 + bias), NC=256, bf16 in/out -------
__global__ __launch_bounds__(256) void gemm_mfma(
    const __hip_bfloat16* __restrict__ A0, const __hip_bfloat16* __restrict__ A1,
    const __hip_bfloat16* __restrict__ W0T, const __hip_bfloat16* __restrict__ W1T,
    const float* __restrict__ bias,
    __hip_bfloat16* __restrict__ Cmat,
    int n, int K0, int K1)
{
    __shared__ __hip_bfloat16 Asl[128 * 64];
    __shared__ __hip_bfloat16 Bsl[128 * 64];
    const int bm = blockIdx.x >> 1;
    const int bn = blockIdx.x & 1;
    const int row0 = bm * 128, col0 = bn * 128;
    const int t = threadIdx.x, lane = t & 63, wid = t >> 6;
    const int wr = wid >> 1, wc = wid & 1;

    f32x4 acc[4][4] = {};

    for (int seg = 0; seg < 2; ++seg) {
        const __hip_bfloat16* A  = seg ? A1 : A0;
        const __hip_bfloat16* WT = seg ? W1T : W0T;
        const int K = seg ? K1 : K0;
        for (int k0 = 0; k0 < K; k0 += 64) {
#pragma unroll
            for (int i = 0; i < 4; ++i) {
                int idx = i * 256 + t;
                int r = idx >> 3, c = idx & 7;
                int gr = row0 + r; if (gr >= n) gr = n - 1;
                const __hip_bfloat16* srcA =
                    A + (size_t)gr * K + k0 + ((c ^ (r & 7)) << 3);
                __builtin_amdgcn_global_load_lds(
                    (const __attribute__((address_space(1))) void*)srcA,
                    (__attribute__((address_space(3))) void*)&Asl[idx * 8], 16, 0, 0);
                const __hip_bfloat16* srcB =
                    WT + (size_t)(col0 + r) * K + k0 + ((c ^ (r & 7)) << 3);
                __builtin_amdgcn_global_load_lds(
                    (const __attribute__((address_space(1))) void*)srcB,
                    (__attribute__((address_space(3))) void*)&Bsl[idx * 8], 16, 0, 0);
            }
            __syncthreads();
#pragma unroll
            for (int kh = 0; kh < 2; ++kh) {
                const int cchunk = kh * 4 + (lane >> 4);
                short8 af[4], bfr[4];
#pragma unroll
                for (int m = 0; m < 4; ++m) {
                    int r = wr * 64 + m * 16 + (lane & 15);
                    af[m] = *(const short8*)&Asl[r * 64 + ((cchunk ^ (r & 7)) << 3)];
                }
#pragma unroll
                for (int nn = 0; nn < 4; ++nn) {
                    int r = wc * 64 + nn * 16 + (lane & 15);
                    bfr[nn] = *(const short8*)&Bsl[r * 64 + ((cchunk ^ (r & 7)) << 3)];
                }
#pragma unroll
                for (int m = 0; m < 4; ++m)
#pragma unroll
                    for (int nn = 0; nn < 4; ++nn)
                        acc[m][nn] = __builtin_amdgcn_mfma_f32_16x16x32_bf16(
                            af[m], bfr[nn], acc[m][nn], 0, 0, 0);
            }
            __syncthreads();
        }
    }

#pragma unroll
    for (int nn = 0; nn < 4; ++nn) {
        int col = col0 + wc * 64 + nn * 16 + (lane & 15);
        float b = bias[col];
#pragma unroll
        for (int m = 0; m < 4; ++m) {
#pragma unroll
            for (int rg = 0; rg < 4; ++rg) {
                int row = row0 + wr * 64 + m * 16 + ((lane >> 4) * 4) + rg;
                if (row < n) {
                    float v = fmaxf(acc[m][nn][rg] + b, 0.f);
                    Cmat[(size_t)row * 256 + col] = __float2bfloat16(v);
                }
            }
        }
    }
}

// ---- head: out = log_softmax([x1|x2] @ w_lin + b_lin), MFMA fused ---------
__global__ __launch_bounds__(256) void head_mfma(
    const __hip_bfloat16* __restrict__ X1, const __hip_bfloat16* __restrict__ X2,
    const __hip_bfloat16* __restrict__ WLT,   // [2][64][256]
    const float* __restrict__ b_lin,
    float* __restrict__ out, int n)
{
    __shared__ __hip_bfloat16 Asl[128 * 64];
    __shared__ __hip_bfloat16 Bsl[64 * 64];
    const int row0 = blockIdx.x * 128;
    const int t = threadIdx.x, lane = t & 63, wid = t >> 6;

    f32x4 acc[2][4] = {};

    for (int seg = 0; seg < 2; ++seg) {
        const __hip_bfloat16* A  = seg ? X2 : X1;
        const __hip_bfloat16* WT = WLT + seg * 64 * 256;
        for (int k0 = 0; k0 < 256; k0 += 64) {
#pragma unroll
            for (int i = 0; i < 4; ++i) {
                int idx = i * 256 + t;
                int r = idx >> 3, c = idx & 7;
                int gr = row0 + r; if (gr >= n) gr = n - 1;
                const __hip_bfloat16* srcA =
                    A + (size_t)gr * 256 + k0 + ((c ^ (r & 7)) << 3);
                __builtin_amdgcn_global_load_lds(
                    (const __attribute__((address_space(1))) void*)srcA,
                    (__attribute__((address_space(3))) void*)&Asl[idx * 8], 16, 0, 0);
            }
#pragma unroll
            for (int i = 0; i < 2; ++i) {
                int idx = i * 256 + t;
                int r = idx >> 3, c = idx & 7;
                const __hip_bfloat16* srcB =
                    WT + (size_t)r * 256 + k0 + ((c ^ (r & 7)) << 3);
                __builtin_amdgcn_global_load_lds(
                    (const __attribute__((address_space(1))) void*)srcB,
                    (__attribute__((address_space(3))) void*)&Bsl[idx * 8], 16, 0, 0);
            }
            __syncthreads();
#pragma unroll
            for (int kh = 0; kh < 2; ++kh) {
                const int cchunk = kh * 4 + (lane >> 4);
                short8 af[2], bfr[4];
#pragma unroll
                for (int m = 0; m < 2; ++m) {
                    int r = wid * 32 + m * 16 + (lane & 15);
                    af[m] = *(const short8*)&Asl[r * 64 + ((cchunk ^ (r & 7)) << 3)];
                }
#pragma unroll
                for (int nn = 0; nn < 4; ++nn) {
                    int r = nn * 16 + (lane & 15);
                    bfr[nn] = *(const short8*)&Bsl[r * 64 + ((cchunk ^ (r & 7)) << 3)];
                }
#pragma unroll
                for (int m = 0; m < 2; ++m)
#pragma unroll
                    for (int nn = 0; nn < 4; ++nn)
                        acc[m][nn] = __builtin_amdgcn_mfma_f32_16x16x32_bf16(
                            af[m], bfr[nn], acc[m][nn], 0, 0, 0);
            }
            __syncthreads();
        }
    }

    const int cl = lane & 15;
    float bb[4];
#pragma unroll
    for (int nn = 0; nn < 4; ++nn) {
        int col = nn * 16 + cl;
        bb[nn] = (col < 40) ? b_lin[col] : 0.f;
    }
#pragma unroll
    for (int m = 0; m < 2; ++m) {
#pragma unroll
        for (int rg = 0; rg < 4; ++rg) {
            float v[4];
            float mx = -1e30f;
#pragma unroll
            for (int nn = 0; nn < 4; ++nn) {
                int col = nn * 16 + cl;
                v[nn] = acc[m][nn][rg] + bb[nn];
                if (col < 40) mx = fmaxf(mx, v[nn]);
            }
#pragma unroll
            for (int off = 1; off < 16; off <<= 1)
                mx = fmaxf(mx, __shfl_xor(mx, off, 64));
            float s = 0.f;
#pragma unroll
            for (int nn = 0; nn < 4; ++nn) {
                int col = nn * 16 + cl;
                if (col < 40) s += expf(v[nn] - mx);
            }
#pragma unroll
            for (int off = 1; off < 16; off <<= 1)
                s += __shfl_xor(s, off, 64);
            float ls = logf(s);
            int row = row0 + wid * 32 + m * 16 + ((lane >> 4) * 4) + rg;
            if (row < n) {
#pragma unroll
                for (int nn = 0; nn < 4; ++nn) {
                    int col = nn * 16 + cl;
                    if (col < 40)
                        out[(size_t)row * 40 + col] = v[nn] - mx - ls;
                }
            }
        }
    }
}

// ---------------------------------------------------------------------------
extern "C" void kernel_launch(void* const* d_in, const int* in_sizes, int n_in,
                              void* d_out, int out_size, void* d_ws, size_t ws_size,
                              hipStream_t stream)
{
    const float* x       = (const float*)d_in[0];
    const int*   ei      = (const int*)  d_in[1];
    const float* ew      = (const float*)d_in[2];
    const float* w1_rel  = (const float*)d_in[3];
    const float* b1      = (const float*)d_in[4];
    const float* w1_root = (const float*)d_in[5];
    const float* w2_rel  = (const float*)d_in[6];
    const float* b2      = (const float*)d_in[7];
    const float* w2_root = (const float*)d_in[8];
    const float* w_lin   = (const float*)d_in[9];
    const float* b_lin   = (const float*)d_in[10];
    float* out = (float*)d_out;

    const int N = in_sizes[0] / 128;   // 50000
    const int E = in_sizes[2];         // 800000

    auto align = [](char*& p, size_t bytes) {
        char* r = p;
        p += (bytes + 255) & ~(size_t)255;
        return r;
    };
    char* wp = (char*)d_ws;
    __hip_bfloat16* xb     = (__hip_bfloat16*)align(wp, (size_t)N * 128 * 2);
    __hip_bfloat16* agg1b  = (__hip_bfloat16*)align(wp, (size_t)N * 128 * 2);
    __hip_bfloat16* x1b    = (__hip_bfloat16*)align(wp, (size_t)N * 256 * 2);
    __hip_bfloat16* agg2b  = (__hip_bfloat16*)align(wp, (size_t)N * 256 * 2);
    __hip_bfloat16* x2b    = (__hip_bfloat16*)align(wp, (size_t)N * 256 * 2);
    __hip_bfloat16* w1relT  = (__hip_bfloat16*)align(wp, 256 * 128 * 2);
    __hip_bfloat16* w1rootT = (__hip_bfloat16*)align(wp, 256 * 128 * 2);
    __hip_bfloat16* w2relT  = (__hip_bfloat16*)align(wp, 256 * 256 * 2);
    __hip_bfloat16* w2rootT = (__hip_bfloat16*)align(wp, 256 * 256 * 2);
    __hip_bfloat16* wlinT   = (__hip_bfloat16*)align(wp, 2 * 64 * 256 * 2);
    int*   counts  = (int*)align(wp, (size_t)N * 4);
    int*   row_ptr = (int*)align(wp, (size_t)(N + 1) * 4);
    int*   cursor  = (int*)align(wp, (size_t)N * 4);
    int*   bsum    = (int*)align(wp, 256 * 4);
    int*   bpre    = (int*)align(wp, 256 * 4);
    int2*  edges   = (int2*)align(wp, (size_t)E * 8);

    const int eb = (E + 255) / 256;
    const int nb = (N + 255) / 256;   // 196 <= 256

    hipMemsetAsync(counts, 0, (size_t)N * 4, stream);
    const int NX8 = N * 128 / 8;       // 800000
    {
        long long total = (long long)E + NX8 + 229376;
        int blocks = (int)((total + 255) / 256);
        prep_all<<<blocks, 256, 0, stream>>>(
            ei, counts, E, x, xb, NX8,
            w1_rel, w1_root, w2_rel, w2_root, w_lin,
            w1relT, w1rootT, w2relT, w2rootT, wlinT);
    }
    scan_block_sums<<<nb, 256, 0, stream>>>(counts, bsum, N);
    scan_bsum<<<1, 256, 0, stream>>>(bsum, bpre, nb);
    scan_final<<<nb, 256, 0, stream>>>(counts, bpre, row_ptr, cursor, N, E);
    fill_kernel<<<eb, 256, 0, stream>>>(ei, ew, cursor, edges, E);

    const int gather_blocks = (N * 64 + 255) / 256;
    const int gemm_grid     = ((N + 127) / 128) * 2;
    const int head_grid     = (N + 127) / 128;

    // layer 1
    gather_bf16<128><<<gather_blocks, 256, 0, stream>>>(
        xb, edges, row_ptr, agg1b, N);
    gemm_mfma<<<gemm_grid, 256, 0, stream>>>(
        agg1b, xb, w1relT, w1rootT, b1, x1b, N, 128, 128);
    // layer 2
    gather_bf16<256><<<gather_blocks, 256, 0, stream>>>(
        x1b, edges, row_ptr, agg2b, N);
    gemm_mfma<<<gemm_grid, 256, 0, stream>>>(
        agg2b, x1b, w2relT, w2rootT, b2, x2b, N, 256, 256);
    // head
    head_mfma<<<head_grid, 256, 0, stream>>>(x1b, x2b, wlinT, b_lin, out, N);
}

// Round 9
// 259.291 us; speedup vs baseline: 1.0516x; 1.0516x over previous
//
#include <hip/hip_runtime.h>
#include <hip/hip_bf16.h>
#include <hip/hip_fp16.h>
#include <math.h>

// ---------------------------------------------------------------------------
// GraphConv GNN, round 8: fp8-e4m3 message table for the gathers (halves the
// fabric bytes of the byte-bound stage). fp32 accumulation, bf16 GEMM path
// unchanged. Decode via v_cvt_pk_f32_fp8 (guarded), encode via half-trick.
// ---------------------------------------------------------------------------

typedef __attribute__((ext_vector_type(8))) short short8;
typedef __attribute__((ext_vector_type(4))) float f32x4;

static __device__ __forceinline__ float bf2f(unsigned short u) {
    return __uint_as_float(((unsigned)u) << 16);
}

// ---- fp8 e4m3 helpers -----------------------------------------------------
static __device__ __forceinline__ void fp8x4_to_f32(unsigned u, float* o) {
#if __has_builtin(__builtin_amdgcn_cvt_pk_f32_fp8)
    auto lo = __builtin_amdgcn_cvt_pk_f32_fp8((int)u, false);
    auto hi = __builtin_amdgcn_cvt_pk_f32_fp8((int)u, true);
    o[0] = lo[0]; o[1] = lo[1]; o[2] = hi[0]; o[3] = hi[1];
#else
#pragma unroll
    for (int i = 0; i < 4; ++i) {
        unsigned b = (u >> (8 * i)) & 0xffu;
        unsigned short hb = (unsigned short)(((b & 0x80u) << 8) | ((b & 0x7fu) << 7));
        o[i] = __half2float(__ushort_as_half(hb)) * 256.0f;
    }
#endif
}

static __device__ __forceinline__ unsigned f32_to_fp8(float f) {
    __half h = __float2half(f * 0.00390625f);            // 2^-8
    unsigned short hb = __half_as_ushort(h);
    unsigned mag = hb & 0x7fffu;
    unsigned s = (hb >> 8) & 0x80u;
    unsigned v = (mag + 0x3fu + ((mag >> 7) & 1u)) >> 7; // RNE
    if (v > 0x7eu) v = 0x7eu;                            // clamp below NaN
    return s | v;
}

// ---- CSR scan -------------------------------------------------------------
__global__ __launch_bounds__(256) void scan_block_sums(
    const int* __restrict__ counts, int* __restrict__ bsum, int n)
{
    __shared__ int sh[256];
    int idx = blockIdx.x * 256 + threadIdx.x;
    sh[threadIdx.x] = (idx < n) ? counts[idx] : 0;
    __syncthreads();
#pragma unroll
    for (int off = 128; off; off >>= 1) {
        if (threadIdx.x < off) sh[threadIdx.x] += sh[threadIdx.x + off];
        __syncthreads();
    }
    if (threadIdx.x == 0) bsum[blockIdx.x] = sh[0];
}

__global__ __launch_bounds__(256) void scan_bsum(
    const int* __restrict__ bsum, int* __restrict__ bpre, int nb)
{
    __shared__ int sh[256];
    int t = threadIdx.x;
    int v = (t < nb) ? bsum[t] : 0;
    sh[t] = v;
    __syncthreads();
#pragma unroll
    for (int off = 1; off < 256; off <<= 1) {
        int u = (t >= off) ? sh[t - off] : 0;
        __syncthreads();
        sh[t] += u;
        __syncthreads();
    }
    bpre[t] = sh[t] - v;   // exclusive
}

__global__ __launch_bounds__(256) void scan_final(
    const int* __restrict__ counts, const int* __restrict__ bpre,
    int* __restrict__ row_ptr, int* __restrict__ cursor, int n, int Etot)
{
    __shared__ int sh[256];
    int t = threadIdx.x;
    int idx = blockIdx.x * 256 + t;
    int v = (idx < n) ? counts[idx] : 0;
    sh[t] = v;
    __syncthreads();
#pragma unroll
    for (int off = 1; off < 256; off <<= 1) {
        int u = (t >= off) ? sh[t - off] : 0;
        __syncthreads();
        sh[t] += u;
        __syncthreads();
    }
    if (idx < n) {
        int val = bpre[blockIdx.x] + sh[t] - v;
        row_ptr[idx] = val;
        cursor[idx]  = val;
    }
    if (idx == 0) row_ptr[n] = Etot;
}

__global__ __launch_bounds__(256) void fill_kernel(
    const int* __restrict__ ei, const float* __restrict__ ew,
    int* __restrict__ cursor, int2* __restrict__ edges, int E)
{
    int e = blockIdx.x * 256 + threadIdx.x;
    if (e >= E) return;
    int d = ei[E + e];
    int p = atomicAdd(&cursor[d], 1);
    edges[p] = make_int2(ei[e], __float_as_int(ew[e]));
}

// ---- fused prep: count atomics + x->bf16+fp8 + weight transposes ----------
__global__ __launch_bounds__(256) void prep_all(
    const int* __restrict__ ei, int* __restrict__ counts, int E,
    const float* __restrict__ x, __hip_bfloat16* __restrict__ xb,
    unsigned char* __restrict__ xb8, int NX8,
    const float* __restrict__ w1_rel, const float* __restrict__ w1_root,
    const float* __restrict__ w2_rel, const float* __restrict__ w2_root,
    const float* __restrict__ w_lin,
    __hip_bfloat16* __restrict__ w1relT, __hip_bfloat16* __restrict__ w1rootT,
    __hip_bfloat16* __restrict__ w2relT, __hip_bfloat16* __restrict__ w2rootT,
    __hip_bfloat16* __restrict__ wlinT)
{
    int idx = blockIdx.x * 256 + threadIdx.x;
    if (idx < E) {
        atomicAdd(&counts[ei[E + idx]], 1);
        return;
    }
    idx -= E;
    if (idx < NX8) {   // x -> bf16 + fp8, 8 elems/thread
        float4 a = *(const float4*)&x[(size_t)idx * 8];
        float4 b = *(const float4*)&x[(size_t)idx * 8 + 4];
        float f[8] = { a.x, a.y, a.z, a.w, b.x, b.y, b.z, b.w };
        __hip_bfloat16 o[8];
#pragma unroll
        for (int i = 0; i < 8; ++i) o[i] = __float2bfloat16(f[i]);
        *(short8*)&xb[(size_t)idx * 8] = *(short8*)o;
        unsigned p0 = 0, p1 = 0;
#pragma unroll
        for (int i = 0; i < 4; ++i) p0 |= f32_to_fp8(f[i]) << (8 * i);
#pragma unroll
        for (int i = 0; i < 4; ++i) p1 |= f32_to_fp8(f[4 + i]) << (8 * i);
        *(uint2*)&xb8[(size_t)idx * 8] = make_uint2(p0, p1);
        return;
    }
    idx -= NX8;
    if (idx < 65536) {                       // w1_rel/w1_root [128,256] -> [256,128]
        const float* src = (idx < 32768) ? w1_rel : w1_root;
        __hip_bfloat16* dst = (idx < 32768) ? w1relT : w1rootT;
        int i = idx & 32767;
        int k = i >> 8, c = i & 255;
        dst[c * 128 + k] = __float2bfloat16(src[i]);
    } else if (idx < 196608) {               // w2_rel/w2_root [256,256]^T
        int j = idx - 65536;
        const float* src = (j < 65536) ? w2_rel : w2_root;
        __hip_bfloat16* dst = (j < 65536) ? w2relT : w2rootT;
        int i = j & 65535;
        int k = i >> 8, c = i & 255;
        dst[c * 256 + k] = __float2bfloat16(src[i]);
    } else if (idx < 229376) {               // w_lin [512,40] -> [2][64][256]
        int i = idx - 196608;
        int seg = i >> 14, c = (i >> 8) & 63, k = i & 255;
        float v = (c < 40) ? w_lin[(size_t)(seg * 256 + k) * 40 + c] : 0.f;
        wlinT[i] = __float2bfloat16(v);
    }
}

// ---- gather (fp8 table): agg[v,:] = sum_e w_e * feat8[src_e,:] ------------
// One wave per node; 16 B load = 16 fp8 elements per lane.
//   C=128: 8 lanes/row, EPW=8.   C=256: 16 lanes/row, EPW=4.
// Edge chunk loaded coalesced, padding lanes carry weight 0 (shfl-safe).
template <int C>
__global__ __launch_bounds__(256) void gather_fp8(
    const unsigned char* __restrict__ feat8,
    const int2* __restrict__ edges,
    const int*  __restrict__ rp,
    __hip_bfloat16* __restrict__ agg, int n)
{
    const int node = (blockIdx.x * 256 + threadIdx.x) >> 6;
    const int lane = threadIdx.x & 63;
    if (node >= n) return;
    const int beg = __builtin_amdgcn_readfirstlane(rp[node]);
    const int end = __builtin_amdgcn_readfirstlane(rp[node + 1]);

    constexpr int EPW = (C == 128) ? 8 : 4;       // edge slots per step
    constexpr int LPR = 64 / EPW;                 // lanes per row
    const int es = lane / LPR;
    const int ch = lane % LPR;
    const unsigned coff = (unsigned)ch * 16;      // byte offset of 16-elem chunk

    float acc[16] = {};

    auto accum16 = [&](uint4 u, float w) {
        unsigned uu[4] = { u.x, u.y, u.z, u.w };
#pragma unroll
        for (int q = 0; q < 4; ++q) {
            float f[4];
            fp8x4_to_f32(uu[q], f);
#pragma unroll
            for (int i = 0; i < 4; ++i)
                acc[q * 4 + i] = fmaf(f[i], w, acc[q * 4 + i]);
        }
    };

    for (int base = beg; base < end; base += 64) {
        const int m = min(64, end - base);
        int2 ev = edges[base + ((lane < m) ? lane : (m - 1))];
        if (lane >= m) ev.y = 0;

        int s = 0;
        for (; s + 2 * EPW <= m; s += 2 * EPW) {
            int j0 = s + es, j1 = j0 + EPW;
            int   s0 = __shfl(ev.x, j0, 64), s1 = __shfl(ev.x, j1, 64);
            float w0 = __int_as_float(__shfl(ev.y, j0, 64));
            float w1 = __int_as_float(__shfl(ev.y, j1, 64));
            uint4 u0 = *(const uint4*)(feat8 + (size_t)(unsigned)s0 * C + coff);
            uint4 u1 = *(const uint4*)(feat8 + (size_t)(unsigned)s1 * C + coff);
            accum16(u0, w0);
            accum16(u1, w1);
        }
        for (; s < m; s += EPW) {
            int j = min(s + es, 63);
            int   sj = __shfl(ev.x, j, 64);
            float wj = __int_as_float(__shfl(ev.y, j, 64));
            uint4 u = *(const uint4*)(feat8 + (size_t)(unsigned)sj * C + coff);
            accum16(u, wj);
        }
    }

    // fold edge slots
#pragma unroll
    for (int k = 0; k < 16; ++k) {
        if constexpr (C == 128) {
            acc[k] += __shfl_xor(acc[k], 8, 64);
            acc[k] += __shfl_xor(acc[k], 16, 64);
            acc[k] += __shfl_xor(acc[k], 32, 64);
        } else {
            acc[k] += __shfl_xor(acc[k], 16, 64);
            acc[k] += __shfl_xor(acc[k], 32, 64);
        }
    }
    if (es == 0) {
        __hip_bfloat16 o[16];
#pragma unroll
        for (int k = 0; k < 16; ++k) o[k] = __float2bfloat16(acc[k]);
        __hip_bfloat16* op = agg + (size_t)node * C + ch * 16;
        *(short8*)op       = *(short8*)o;
        *(short8*)(op + 8) = *(short8*)(o + 8);
    }
}

// ---- MFMA GEMM: C = relu(A0@W0 + A1@W1 + bias), NC=256, bf16 in/out -------
// WRITE_FP8: additionally emit the fp8 message table of the output.
template <bool WRITE_FP8>
__global__ __launch_bounds__(256) void gemm_mfma(
    const __hip_bfloat16* __restrict__ A0, const __hip_bfloat16* __restrict__ A1,
    const __hip_bfloat16* __restrict__ W0T, const __hip_bfloat16* __restrict__ W1T,
    const float* __restrict__ bias,
    __hip_bfloat16* __restrict__ Cmat,
    unsigned char* __restrict__ Cfp8,
    int n, int K0, int K1)
{
    __shared__ __hip_bfloat16 Asl[128 * 64];
    __shared__ __hip_bfloat16 Bsl[128 * 64];
    const int bm = blockIdx.x >> 1;
    const int bn = blockIdx.x & 1;
    const int row0 = bm * 128, col0 = bn * 128;
    const int t = threadIdx.x, lane = t & 63, wid = t >> 6;
    const int wr = wid >> 1, wc = wid & 1;

    f32x4 acc[4][4] = {};

    for (int seg = 0; seg < 2; ++seg) {
        const __hip_bfloat16* A  = seg ? A1 : A0;
        const __hip_bfloat16* WT = seg ? W1T : W0T;
        const int K = seg ? K1 : K0;
        for (int k0 = 0; k0 < K; k0 += 64) {
#pragma unroll
            for (int i = 0; i < 4; ++i) {
                int idx = i * 256 + t;
                int r = idx >> 3, c = idx & 7;
                int gr = row0 + r; if (gr >= n) gr = n - 1;
                const __hip_bfloat16* srcA =
                    A + (size_t)gr * K + k0 + ((c ^ (r & 7)) << 3);
                __builtin_amdgcn_global_load_lds(
                    (const __attribute__((address_space(1))) void*)srcA,
                    (__attribute__((address_space(3))) void*)&Asl[idx * 8], 16, 0, 0);
                const __hip_bfloat16* srcB =
                    WT + (size_t)(col0 + r) * K + k0 + ((c ^ (r & 7)) << 3);
                __builtin_amdgcn_global_load_lds(
                    (const __attribute__((address_space(1))) void*)srcB,
                    (__attribute__((address_space(3))) void*)&Bsl[idx * 8], 16, 0, 0);
            }
            __syncthreads();
#pragma unroll
            for (int kh = 0; kh < 2; ++kh) {
                const int cchunk = kh * 4 + (lane >> 4);
                short8 af[4], bfr[4];
#pragma unroll
                for (int m = 0; m < 4; ++m) {
                    int r = wr * 64 + m * 16 + (lane & 15);
                    af[m] = *(const short8*)&Asl[r * 64 + ((cchunk ^ (r & 7)) << 3)];
                }
#pragma unroll
                for (int nn = 0; nn < 4; ++nn) {
                    int r = wc * 64 + nn * 16 + (lane & 15);
                    bfr[nn] = *(const short8*)&Bsl[r * 64 + ((cchunk ^ (r & 7)) << 3)];
                }
#pragma unroll
                for (int m = 0; m < 4; ++m)
#pragma unroll
                    for (int nn = 0; nn < 4; ++nn)
                        acc[m][nn] = __builtin_amdgcn_mfma_f32_16x16x32_bf16(
                            af[m], bfr[nn], acc[m][nn], 0, 0, 0);
            }
            __syncthreads();
        }
    }

#pragma unroll
    for (int nn = 0; nn < 4; ++nn) {
        int col = col0 + wc * 64 + nn * 16 + (lane & 15);
        float b = bias[col];
#pragma unroll
        for (int m = 0; m < 4; ++m) {
#pragma unroll
            for (int rg = 0; rg < 4; ++rg) {
                int row = row0 + wr * 64 + m * 16 + ((lane >> 4) * 4) + rg;
                if (row < n) {
                    float v = fmaxf(acc[m][nn][rg] + b, 0.f);
                    Cmat[(size_t)row * 256 + col] = __float2bfloat16(v);
                    if constexpr (WRITE_FP8)
                        Cfp8[(size_t)row * 256 + col] = (unsigned char)f32_to_fp8(v);
                }
            }
        }
    }
}

// ---- head: out = log_softmax([x1|x2] @ w_lin + b_lin), MFMA fused ---------
__global__ __launch_bounds__(256) void head_mfma(
    const __hip_bfloat16* __restrict__ X1, const __hip_bfloat16* __restrict__ X2,
    const __hip_bfloat16* __restrict__ WLT,   // [2][64][256]
    const float* __restrict__ b_lin,
    float* __restrict__ out, int n)
{
    __shared__ __hip_bfloat16 Asl[128 * 64];
    __shared__ __hip_bfloat16 Bsl[64 * 64];
    const int row0 = blockIdx.x * 128;
    const int t = threadIdx.x, lane = t & 63, wid = t >> 6;

    f32x4 acc[2][4] = {};

    for (int seg = 0; seg < 2; ++seg) {
        const __hip_bfloat16* A  = seg ? X2 : X1;
        const __hip_bfloat16* WT = WLT + seg * 64 * 256;
        for (int k0 = 0; k0 < 256; k0 += 64) {
#pragma unroll
            for (int i = 0; i < 4; ++i) {
                int idx = i * 256 + t;
                int r = idx >> 3, c = idx & 7;
                int gr = row0 + r; if (gr >= n) gr = n - 1;
                const __hip_bfloat16* srcA =
                    A + (size_t)gr * 256 + k0 + ((c ^ (r & 7)) << 3);
                __builtin_amdgcn_global_load_lds(
                    (const __attribute__((address_space(1))) void*)srcA,
                    (__attribute__((address_space(3))) void*)&Asl[idx * 8], 16, 0, 0);
            }
#pragma unroll
            for (int i = 0; i < 2; ++i) {
                int idx = i * 256 + t;
                int r = idx >> 3, c = idx & 7;
                const __hip_bfloat16* srcB =
                    WT + (size_t)r * 256 + k0 + ((c ^ (r & 7)) << 3);
                __builtin_amdgcn_global_load_lds(
                    (const __attribute__((address_space(1))) void*)srcB,
                    (__attribute__((address_space(3))) void*)&Bsl[idx * 8], 16, 0, 0);
            }
            __syncthreads();
#pragma unroll
            for (int kh = 0; kh < 2; ++kh) {
                const int cchunk = kh * 4 + (lane >> 4);
                short8 af[2], bfr[4];
#pragma unroll
                for (int m = 0; m < 2; ++m) {
                    int r = wid * 32 + m * 16 + (lane & 15);
                    af[m] = *(const short8*)&Asl[r * 64 + ((cchunk ^ (r & 7)) << 3)];
                }
#pragma unroll
                for (int nn = 0; nn < 4; ++nn) {
                    int r = nn * 16 + (lane & 15);
                    bfr[nn] = *(const short8*)&Bsl[r * 64 + ((cchunk ^ (r & 7)) << 3)];
                }
#pragma unroll
                for (int m = 0; m < 2; ++m)
#pragma unroll
                    for (int nn = 0; nn < 4; ++nn)
                        acc[m][nn] = __builtin_amdgcn_mfma_f32_16x16x32_bf16(
                            af[m], bfr[nn], acc[m][nn], 0, 0, 0);
            }
            __syncthreads();
        }
    }

    const int cl = lane & 15;
    float bb[4];
#pragma unroll
    for (int nn = 0; nn < 4; ++nn) {
        int col = nn * 16 + cl;
        bb[nn] = (col < 40) ? b_lin[col] : 0.f;
    }
#pragma unroll
    for (int m = 0; m < 2; ++m) {
#pragma unroll
        for (int rg = 0; rg < 4; ++rg) {
            float v[4];
            float mx = -1e30f;
#pragma unroll
            for (int nn = 0; nn < 4; ++nn) {
                int col = nn * 16 + cl;
                v[nn] = acc[m][nn][rg] + bb[nn];
                if (col < 40) mx = fmaxf(mx, v[nn]);
            }
#pragma unroll
            for (int off = 1; off < 16; off <<= 1)
                mx = fmaxf(mx, __shfl_xor(mx, off, 64));
            float s = 0.f;
#pragma unroll
            for (int nn = 0; nn < 4; ++nn) {
                int col = nn * 16 + cl;
                if (col < 40) s += expf(v[nn] - mx);
            }
#pragma unroll
            for (int off = 1; off < 16; off <<= 1)
                s += __shfl_xor(s, off, 64);
            float ls = logf(s);
            int row = row0 + wid * 32 + m * 16 + ((lane >> 4) * 4) + rg;
            if (row < n) {
#pragma unroll
                for (int nn = 0; nn < 4; ++nn) {
                    int col = nn * 16 + cl;
                    if (col < 40)
                        out[(size_t)row * 40 + col] = v[nn] - mx - ls;
                }
            }
        }
    }
}

// ---------------------------------------------------------------------------
extern "C" void kernel_launch(void* const* d_in, const int* in_sizes, int n_in,
                              void* d_out, int out_size, void* d_ws, size_t ws_size,
                              hipStream_t stream)
{
    const float* x       = (const float*)d_in[0];
    const int*   ei      = (const int*)  d_in[1];
    const float* ew      = (const float*)d_in[2];
    const float* w1_rel  = (const float*)d_in[3];
    const float* b1      = (const float*)d_in[4];
    const float* w1_root = (const float*)d_in[5];
    const float* w2_rel  = (const float*)d_in[6];
    const float* b2      = (const float*)d_in[7];
    const float* w2_root = (const float*)d_in[8];
    const float* w_lin   = (const float*)d_in[9];
    const float* b_lin   = (const float*)d_in[10];
    float* out = (float*)d_out;

    const int N = in_sizes[0] / 128;   // 50000
    const int E = in_sizes[2];         // 800000

    auto align = [](char*& p, size_t bytes) {
        char* r = p;
        p += (bytes + 255) & ~(size_t)255;
        return r;
    };
    char* wp = (char*)d_ws;
    __hip_bfloat16* xb     = (__hip_bfloat16*)align(wp, (size_t)N * 128 * 2);
    __hip_bfloat16* agg1b  = (__hip_bfloat16*)align(wp, (size_t)N * 128 * 2);
    __hip_bfloat16* x1b    = (__hip_bfloat16*)align(wp, (size_t)N * 256 * 2);
    __hip_bfloat16* agg2b  = (__hip_bfloat16*)align(wp, (size_t)N * 256 * 2);
    __hip_bfloat16* x2b    = (__hip_bfloat16*)align(wp, (size_t)N * 256 * 2);
    unsigned char*  xb8    = (unsigned char*)align(wp, (size_t)N * 128);
    unsigned char*  x1b8   = (unsigned char*)align(wp, (size_t)N * 256);
    __hip_bfloat16* w1relT  = (__hip_bfloat16*)align(wp, 256 * 128 * 2);
    __hip_bfloat16* w1rootT = (__hip_bfloat16*)align(wp, 256 * 128 * 2);
    __hip_bfloat16* w2relT  = (__hip_bfloat16*)align(wp, 256 * 256 * 2);
    __hip_bfloat16* w2rootT = (__hip_bfloat16*)align(wp, 256 * 256 * 2);
    __hip_bfloat16* wlinT   = (__hip_bfloat16*)align(wp, 2 * 64 * 256 * 2);
    int*   counts  = (int*)align(wp, (size_t)N * 4);
    int*   row_ptr = (int*)align(wp, (size_t)(N + 1) * 4);
    int*   cursor  = (int*)align(wp, (size_t)N * 4);
    int*   bsum    = (int*)align(wp, 256 * 4);
    int*   bpre    = (int*)align(wp, 256 * 4);
    int2*  edges   = (int2*)align(wp, (size_t)E * 8);

    const int eb = (E + 255) / 256;
    const int nb = (N + 255) / 256;   // 196 <= 256

    hipMemsetAsync(counts, 0, (size_t)N * 4, stream);
    const int NX8 = N * 128 / 8;       // 800000
    {
        long long total = (long long)E + NX8 + 229376;
        int blocks = (int)((total + 255) / 256);
        prep_all<<<blocks, 256, 0, stream>>>(
            ei, counts, E, x, xb, xb8, NX8,
            w1_rel, w1_root, w2_rel, w2_root, w_lin,
            w1relT, w1rootT, w2relT, w2rootT, wlinT);
    }
    scan_block_sums<<<nb, 256, 0, stream>>>(counts, bsum, N);
    scan_bsum<<<1, 256, 0, stream>>>(bsum, bpre, nb);
    scan_final<<<nb, 256, 0, stream>>>(counts, bpre, row_ptr, cursor, N, E);
    fill_kernel<<<eb, 256, 0, stream>>>(ei, ew, cursor, edges, E);

    const int gather_blocks = (N * 64 + 255) / 256;
    const int gemm_grid     = ((N + 127) / 128) * 2;
    const int head_grid     = (N + 127) / 128;

    // layer 1
    gather_fp8<128><<<gather_blocks, 256, 0, stream>>>(
        xb8, edges, row_ptr, agg1b, N);
    gemm_mfma<true><<<gemm_grid, 256, 0, stream>>>(
        agg1b, xb, w1relT, w1rootT, b1, x1b, x1b8, N, 128, 128);
    // layer 2
    gather_fp8<256><<<gather_blocks, 256, 0, stream>>>(
        x1b8, edges, row_ptr, agg2b, N);
    gemm_mfma<false><<<gemm_grid, 256, 0, stream>>>(
        agg2b, x1b, w2relT, w2rootT, b2, x2b, nullptr, N, 256, 256);
    // head
    head_mfma<<<head_grid, 256, 0, stream>>>(x1b, x2b, wlinT, b_lin, out, N);
}

// Round 10
// 231.880 us; speedup vs baseline: 1.1759x; 1.1182x over previous
//
#include <hip/hip_runtime.h>
#include <hip/hip_bf16.h>
#include <hip/hip_fp16.h>
#include <math.h>

// ---------------------------------------------------------------------------
// GraphConv GNN, round 9: 2-phase double-buffered MFMA GEMM with LDS-staged
// coalesced epilogue; nontemporal stores in the CSR fill. fp8 gather path
// unchanged from R8.
// ---------------------------------------------------------------------------

typedef __attribute__((ext_vector_type(8))) short short8;
typedef __attribute__((ext_vector_type(4))) float f32x4;

static __device__ __forceinline__ float bf2f(unsigned short u) {
    return __uint_as_float(((unsigned)u) << 16);
}

// ---- fp8 e4m3 helpers -----------------------------------------------------
static __device__ __forceinline__ void fp8x4_to_f32(unsigned u, float* o) {
#if __has_builtin(__builtin_amdgcn_cvt_pk_f32_fp8)
    auto lo = __builtin_amdgcn_cvt_pk_f32_fp8((int)u, false);
    auto hi = __builtin_amdgcn_cvt_pk_f32_fp8((int)u, true);
    o[0] = lo[0]; o[1] = lo[1]; o[2] = hi[0]; o[3] = hi[1];
#else
#pragma unroll
    for (int i = 0; i < 4; ++i) {
        unsigned b = (u >> (8 * i)) & 0xffu;
        unsigned short hb = (unsigned short)(((b & 0x80u) << 8) | ((b & 0x7fu) << 7));
        o[i] = __half2float(__ushort_as_half(hb)) * 256.0f;
    }
#endif
}

static __device__ __forceinline__ unsigned f32_to_fp8(float f) {
    __half h = __float2half(f * 0.00390625f);            // 2^-8
    unsigned short hb = __half_as_ushort(h);
    unsigned mag = hb & 0x7fffu;
    unsigned s = (hb >> 8) & 0x80u;
    unsigned v = (mag + 0x3fu + ((mag >> 7) & 1u)) >> 7; // RNE
    if (v > 0x7eu) v = 0x7eu;                            // clamp below NaN
    return s | v;
}

// ---- CSR scan -------------------------------------------------------------
__global__ __launch_bounds__(256) void scan_block_sums(
    const int* __restrict__ counts, int* __restrict__ bsum, int n)
{
    __shared__ int sh[256];
    int idx = blockIdx.x * 256 + threadIdx.x;
    sh[threadIdx.x] = (idx < n) ? counts[idx] : 0;
    __syncthreads();
#pragma unroll
    for (int off = 128; off; off >>= 1) {
        if (threadIdx.x < off) sh[threadIdx.x] += sh[threadIdx.x + off];
        __syncthreads();
    }
    if (threadIdx.x == 0) bsum[blockIdx.x] = sh[0];
}

__global__ __launch_bounds__(256) void scan_bsum(
    const int* __restrict__ bsum, int* __restrict__ bpre, int nb)
{
    __shared__ int sh[256];
    int t = threadIdx.x;
    int v = (t < nb) ? bsum[t] : 0;
    sh[t] = v;
    __syncthreads();
#pragma unroll
    for (int off = 1; off < 256; off <<= 1) {
        int u = (t >= off) ? sh[t - off] : 0;
        __syncthreads();
        sh[t] += u;
        __syncthreads();
    }
    bpre[t] = sh[t] - v;   // exclusive
}

__global__ __launch_bounds__(256) void scan_final(
    const int* __restrict__ counts, const int* __restrict__ bpre,
    int* __restrict__ row_ptr, int* __restrict__ cursor, int n, int Etot)
{
    __shared__ int sh[256];
    int t = threadIdx.x;
    int idx = blockIdx.x * 256 + t;
    int v = (idx < n) ? counts[idx] : 0;
    sh[t] = v;
    __syncthreads();
#pragma unroll
    for (int off = 1; off < 256; off <<= 1) {
        int u = (t >= off) ? sh[t - off] : 0;
        __syncthreads();
        sh[t] += u;
        __syncthreads();
    }
    if (idx < n) {
        int val = bpre[blockIdx.x] + sh[t] - v;
        row_ptr[idx] = val;
        cursor[idx]  = val;
    }
    if (idx == 0) row_ptr[n] = Etot;
}

__global__ __launch_bounds__(256) void fill_kernel(
    const int* __restrict__ ei, const float* __restrict__ ew,
    int* __restrict__ cursor, int2* __restrict__ edges, int E)
{
    int e = blockIdx.x * 256 + threadIdx.x;
    if (e >= E) return;
    int d = ei[E + e];
    int p = atomicAdd(&cursor[d], 1);
    // nontemporal 8B store: skip read-for-ownership on the random write
    long long v = ((long long)(unsigned)__float_as_int(ew[e]) << 32) |
                  (unsigned)ei[e];
    __builtin_nontemporal_store(v, (long long*)&edges[p]);
}

// ---- fused prep: count atomics + x->bf16+fp8 + weight transposes ----------
__global__ __launch_bounds__(256) void prep_all(
    const int* __restrict__ ei, int* __restrict__ counts, int E,
    const float* __restrict__ x, __hip_bfloat16* __restrict__ xb,
    unsigned char* __restrict__ xb8, int NX8,
    const float* __restrict__ w1_rel, const float* __restrict__ w1_root,
    const float* __restrict__ w2_rel, const float* __restrict__ w2_root,
    const float* __restrict__ w_lin,
    __hip_bfloat16* __restrict__ w1relT, __hip_bfloat16* __restrict__ w1rootT,
    __hip_bfloat16* __restrict__ w2relT, __hip_bfloat16* __restrict__ w2rootT,
    __hip_bfloat16* __restrict__ wlinT)
{
    int idx = blockIdx.x * 256 + threadIdx.x;
    if (idx < E) {
        atomicAdd(&counts[ei[E + idx]], 1);
        return;
    }
    idx -= E;
    if (idx < NX8) {   // x -> bf16 + fp8, 8 elems/thread
        float4 a = *(const float4*)&x[(size_t)idx * 8];
        float4 b = *(const float4*)&x[(size_t)idx * 8 + 4];
        float f[8] = { a.x, a.y, a.z, a.w, b.x, b.y, b.z, b.w };
        __hip_bfloat16 o[8];
#pragma unroll
        for (int i = 0; i < 8; ++i) o[i] = __float2bfloat16(f[i]);
        *(short8*)&xb[(size_t)idx * 8] = *(short8*)o;
        unsigned p0 = 0, p1 = 0;
#pragma unroll
        for (int i = 0; i < 4; ++i) p0 |= f32_to_fp8(f[i]) << (8 * i);
#pragma unroll
        for (int i = 0; i < 4; ++i) p1 |= f32_to_fp8(f[4 + i]) << (8 * i);
        *(uint2*)&xb8[(size_t)idx * 8] = make_uint2(p0, p1);
        return;
    }
    idx -= NX8;
    if (idx < 65536) {                       // w1_rel/w1_root [128,256] -> [256,128]
        const float* src = (idx < 32768) ? w1_rel : w1_root;
        __hip_bfloat16* dst = (idx < 32768) ? w1relT : w1rootT;
        int i = idx & 32767;
        int k = i >> 8, c = i & 255;
        dst[c * 128 + k] = __float2bfloat16(src[i]);
    } else if (idx < 196608) {               // w2_rel/w2_root [256,256]^T
        int j = idx - 65536;
        const float* src = (j < 65536) ? w2_rel : w2_root;
        __hip_bfloat16* dst = (j < 65536) ? w2relT : w2rootT;
        int i = j & 65535;
        int k = i >> 8, c = i & 255;
        dst[c * 256 + k] = __float2bfloat16(src[i]);
    } else if (idx < 229376) {               // w_lin [512,40] -> [2][64][256]
        int i = idx - 196608;
        int seg = i >> 14, c = (i >> 8) & 63, k = i & 255;
        float v = (c < 40) ? w_lin[(size_t)(seg * 256 + k) * 40 + c] : 0.f;
        wlinT[i] = __float2bfloat16(v);
    }
}

// ---- gather (fp8 table): agg[v,:] = sum_e w_e * feat8[src_e,:] ------------
template <int C>
__global__ __launch_bounds__(256) void gather_fp8(
    const unsigned char* __restrict__ feat8,
    const int2* __restrict__ edges,
    const int*  __restrict__ rp,
    __hip_bfloat16* __restrict__ agg, int n)
{
    const int node = (blockIdx.x * 256 + threadIdx.x) >> 6;
    const int lane = threadIdx.x & 63;
    if (node >= n) return;
    const int beg = __builtin_amdgcn_readfirstlane(rp[node]);
    const int end = __builtin_amdgcn_readfirstlane(rp[node + 1]);

    constexpr int EPW = (C == 128) ? 8 : 4;       // edge slots per step
    constexpr int LPR = 64 / EPW;                 // lanes per row
    const int es = lane / LPR;
    const int ch = lane % LPR;
    const unsigned coff = (unsigned)ch * 16;      // byte offset of 16-elem chunk

    float acc[16] = {};

    auto accum16 = [&](uint4 u, float w) {
        unsigned uu[4] = { u.x, u.y, u.z, u.w };
#pragma unroll
        for (int q = 0; q < 4; ++q) {
            float f[4];
            fp8x4_to_f32(uu[q], f);
#pragma unroll
            for (int i = 0; i < 4; ++i)
                acc[q * 4 + i] = fmaf(f[i], w, acc[q * 4 + i]);
        }
    };

    for (int base = beg; base < end; base += 64) {
        const int m = min(64, end - base);
        int2 ev = edges[base + ((lane < m) ? lane : (m - 1))];
        if (lane >= m) ev.y = 0;

        int s = 0;
        for (; s + 2 * EPW <= m; s += 2 * EPW) {
            int j0 = s + es, j1 = j0 + EPW;
            int   s0 = __shfl(ev.x, j0, 64), s1 = __shfl(ev.x, j1, 64);
            float w0 = __int_as_float(__shfl(ev.y, j0, 64));
            float w1 = __int_as_float(__shfl(ev.y, j1, 64));
            uint4 u0 = *(const uint4*)(feat8 + (size_t)(unsigned)s0 * C + coff);
            uint4 u1 = *(const uint4*)(feat8 + (size_t)(unsigned)s1 * C + coff);
            accum16(u0, w0);
            accum16(u1, w1);
        }
        for (; s < m; s += EPW) {
            int j = min(s + es, 63);
            int   sj = __shfl(ev.x, j, 64);
            float wj = __int_as_float(__shfl(ev.y, j, 64));
            uint4 u = *(const uint4*)(feat8 + (size_t)(unsigned)sj * C + coff);
            accum16(u, wj);
        }
    }

#pragma unroll
    for (int k = 0; k < 16; ++k) {
        if constexpr (C == 128) {
            acc[k] += __shfl_xor(acc[k], 8, 64);
            acc[k] += __shfl_xor(acc[k], 16, 64);
            acc[k] += __shfl_xor(acc[k], 32, 64);
        } else {
            acc[k] += __shfl_xor(acc[k], 16, 64);
            acc[k] += __shfl_xor(acc[k], 32, 64);
        }
    }
    if (es == 0) {
        __hip_bfloat16 o[16];
#pragma unroll
        for (int k = 0; k < 16; ++k) o[k] = __float2bfloat16(acc[k]);
        __hip_bfloat16* op = agg + (size_t)node * C + ch * 16;
        *(short8*)op       = *(short8*)o;
        *(short8*)(op + 8) = *(short8*)(o + 8);
    }
}

// ---- MFMA GEMM: C = relu(A0@W0 + A1@W1 + bias), NC=256, bf16 in/out -------
// 2-phase double-buffered K-pipeline; LDS-staged coalesced epilogue.
template <bool WRITE_FP8>
__global__ __launch_bounds__(256) void gemm_mfma(
    const __hip_bfloat16* __restrict__ A0, const __hip_bfloat16* __restrict__ A1,
    const __hip_bfloat16* __restrict__ W0T, const __hip_bfloat16* __restrict__ W1T,
    const float* __restrict__ bias,
    __hip_bfloat16* __restrict__ Cmat,
    unsigned char* __restrict__ Cfp8,
    int n, int K0, int K1)
{
    __shared__ __hip_bfloat16 Asl[2][128 * 64];   // 32 KB
    __shared__ __hip_bfloat16 Bsl[2][128 * 64];   // 32 KB
    const int bm = blockIdx.x >> 1;
    const int bn = blockIdx.x & 1;
    const int row0 = bm * 128, col0 = bn * 128;
    const int t = threadIdx.x, lane = t & 63, wid = t >> 6;
    const int wr = wid >> 1, wc = wid & 1;

    const int S0 = K0 >> 6;                 // steps in segment 0
    const int S  = S0 + (K1 >> 6);          // total K-steps

    auto stage = [&](int buf, int s) {
        const __hip_bfloat16* A;
        const __hip_bfloat16* WT;
        int K, k0;
        if (s < S0) { A = A0; WT = W0T; K = K0; k0 = s << 6; }
        else        { A = A1; WT = W1T; K = K1; k0 = (s - S0) << 6; }
#pragma unroll
        for (int i = 0; i < 4; ++i) {
            int idx = i * 256 + t;
            int r = idx >> 3, c = idx & 7;
            int gr = row0 + r; if (gr >= n) gr = n - 1;
            const __hip_bfloat16* srcA =
                A + (size_t)gr * K + k0 + ((c ^ (r & 7)) << 3);
            __builtin_amdgcn_global_load_lds(
                (const __attribute__((address_space(1))) void*)srcA,
                (__attribute__((address_space(3))) void*)&Asl[buf][idx * 8], 16, 0, 0);
            const __hip_bfloat16* srcB =
                WT + (size_t)(col0 + r) * K + k0 + ((c ^ (r & 7)) << 3);
            __builtin_amdgcn_global_load_lds(
                (const __attribute__((address_space(1))) void*)srcB,
                (__attribute__((address_space(3))) void*)&Bsl[buf][idx * 8], 16, 0, 0);
        }
    };

    f32x4 acc[4][4] = {};

    stage(0, 0);
    __syncthreads();                         // drains step-0 loads (vmcnt(0))

    for (int s = 0; s < S; ++s) {
        const int buf = s & 1;
        if (s + 1 < S) stage(buf ^ 1, s + 1);   // prefetch overlaps MFMA below
#pragma unroll
        for (int kh = 0; kh < 2; ++kh) {
            const int cchunk = kh * 4 + (lane >> 4);
            short8 af[4], bfr[4];
#pragma unroll
            for (int m = 0; m < 4; ++m) {
                int r = wr * 64 + m * 16 + (lane & 15);
                af[m] = *(const short8*)&Asl[buf][r * 64 + ((cchunk ^ (r & 7)) << 3)];
            }
#pragma unroll
            for (int nn = 0; nn < 4; ++nn) {
                int r = wc * 64 + nn * 16 + (lane & 15);
                bfr[nn] = *(const short8*)&Bsl[buf][r * 64 + ((cchunk ^ (r & 7)) << 3)];
            }
#pragma unroll
            for (int m = 0; m < 4; ++m)
#pragma unroll
                for (int nn = 0; nn < 4; ++nn)
                    acc[m][nn] = __builtin_amdgcn_mfma_f32_16x16x32_bf16(
                        af[m], bfr[nn], acc[m][nn], 0, 0, 0);
        }
        __syncthreads();   // drains prefetch (implicit vmcnt0) + guards buf reuse
    }

    // ---- epilogue: bias+relu -> LDS tile -> coalesced global writes -------
    __hip_bfloat16* Csh = &Asl[0][0];        // 128x128 bf16 = 32 KB (Asl both bufs)
#pragma unroll
    for (int nn = 0; nn < 4; ++nn) {
        int lcol = wc * 64 + nn * 16 + (lane & 15);
        float b = bias[col0 + lcol];
#pragma unroll
        for (int m = 0; m < 4; ++m) {
#pragma unroll
            for (int rg = 0; rg < 4; ++rg) {
                int lrow = wr * 64 + m * 16 + ((lane >> 4) * 4) + rg;
                float v = fmaxf(acc[m][nn][rg] + b, 0.f);
                Csh[lrow * 128 + lcol] = __float2bfloat16(v);
            }
        }
    }
    __syncthreads();

    // bf16 out: 128 rows x 128 cols; 16B chunks, 16 chunks/row, 8 iters
#pragma unroll
    for (int it = 0; it < 8; ++it) {
        int idx = it * 256 + t;
        int r = idx >> 4, c16 = idx & 15;
        if (row0 + r < n)
            *(short8*)(Cmat + (size_t)(row0 + r) * 256 + col0 + c16 * 8) =
                *(const short8*)&Csh[r * 128 + c16 * 8];
    }
    if constexpr (WRITE_FP8) {
        // fp8 out: 128 rows x 128 B; 16B chunks, 8 chunks/row, 4 iters
#pragma unroll
        for (int it = 0; it < 4; ++it) {
            int idx = it * 256 + t;
            int r = idx >> 3, c16 = idx & 7;
            if (row0 + r < n) {
                const __hip_bfloat16* src = &Csh[r * 128 + c16 * 16];
                unsigned w[4];
#pragma unroll
                for (int q = 0; q < 4; ++q) {
                    unsigned p = 0;
#pragma unroll
                    for (int i = 0; i < 4; ++i)
                        p |= f32_to_fp8(__bfloat162float(src[q * 4 + i])) << (8 * i);
                    w[q] = p;
                }
                *(uint4*)(Cfp8 + (size_t)(row0 + r) * 256 + col0 + c16 * 16) =
                    make_uint4(w[0], w[1], w[2], w[3]);
            }
        }
    }
}

// ---- head: out = log_softmax([x1|x2] @ w_lin + b_lin), MFMA fused ---------
__global__ __launch_bounds__(256) void head_mfma(
    const __hip_bfloat16* __restrict__ X1, const __hip_bfloat16* __restrict__ X2,
    const __hip_bfloat16* __restrict__ WLT,   // [2][64][256]
    const float* __restrict__ b_lin,
    float* __restrict__ out, int n)
{
    __shared__ __hip_bfloat16 Asl[128 * 64];
    __shared__ __hip_bfloat16 Bsl[64 * 64];
    const int row0 = blockIdx.x * 128;
    const int t = threadIdx.x, lane = t & 63, wid = t >> 6;

    f32x4 acc[2][4] = {};

    for (int seg = 0; seg < 2; ++seg) {
        const __hip_bfloat16* A  = seg ? X2 : X1;
        const __hip_bfloat16* WT = WLT + seg * 64 * 256;
        for (int k0 = 0; k0 < 256; k0 += 64) {
#pragma unroll
            for (int i = 0; i < 4; ++i) {
                int idx = i * 256 + t;
                int r = idx >> 3, c = idx & 7;
                int gr = row0 + r; if (gr >= n) gr = n - 1;
                const __hip_bfloat16* srcA =
                    A + (size_t)gr * 256 + k0 + ((c ^ (r & 7)) << 3);
                __builtin_amdgcn_global_load_lds(
                    (const __attribute__((address_space(1))) void*)srcA,
                    (__attribute__((address_space(3))) void*)&Asl[idx * 8], 16, 0, 0);
            }
#pragma unroll
            for (int i = 0; i < 2; ++i) {
                int idx = i * 256 + t;
                int r = idx >> 3, c = idx & 7;
                const __hip_bfloat16* srcB =
                    WT + (size_t)r * 256 + k0 + ((c ^ (r & 7)) << 3);
                __builtin_amdgcn_global_load_lds(
                    (const __attribute__((address_space(1))) void*)srcB,
                    (__attribute__((address_space(3))) void*)&Bsl[idx * 8], 16, 0, 0);
            }
            __syncthreads();
#pragma unroll
            for (int kh = 0; kh < 2; ++kh) {
                const int cchunk = kh * 4 + (lane >> 4);
                short8 af[2], bfr[4];
#pragma unroll
                for (int m = 0; m < 2; ++m) {
                    int r = wid * 32 + m * 16 + (lane & 15);
                    af[m] = *(const short8*)&Asl[r * 64 + ((cchunk ^ (r & 7)) << 3)];
                }
#pragma unroll
                for (int nn = 0; nn < 4; ++nn) {
                    int r = nn * 16 + (lane & 15);
                    bfr[nn] = *(const short8*)&Bsl[r * 64 + ((cchunk ^ (r & 7)) << 3)];
                }
#pragma unroll
                for (int m = 0; m < 2; ++m)
#pragma unroll
                    for (int nn = 0; nn < 4; ++nn)
                        acc[m][nn] = __builtin_amdgcn_mfma_f32_16x16x32_bf16(
                            af[m], bfr[nn], acc[m][nn], 0, 0, 0);
            }
            __syncthreads();
        }
    }

    const int cl = lane & 15;
    float bb[4];
#pragma unroll
    for (int nn = 0; nn < 4; ++nn) {
        int col = nn * 16 + cl;
        bb[nn] = (col < 40) ? b_lin[col] : 0.f;
    }
#pragma unroll
    for (int m = 0; m < 2; ++m) {
#pragma unroll
        for (int rg = 0; rg < 4; ++rg) {
            float v[4];
            float mx = -1e30f;
#pragma unroll
            for (int nn = 0; nn < 4; ++nn) {
                int col = nn * 16 + cl;
                v[nn] = acc[m][nn][rg] + bb[nn];
                if (col < 40) mx = fmaxf(mx, v[nn]);
            }
#pragma unroll
            for (int off = 1; off < 16; off <<= 1)
                mx = fmaxf(mx, __shfl_xor(mx, off, 64));
            float s = 0.f;
#pragma unroll
            for (int nn = 0; nn < 4; ++nn) {
                int col = nn * 16 + cl;
                if (col < 40) s += expf(v[nn] - mx);
            }
#pragma unroll
            for (int off = 1; off < 16; off <<= 1)
                s += __shfl_xor(s, off, 64);
            float ls = logf(s);
            int row = row0 + wid * 32 + m * 16 + ((lane >> 4) * 4) + rg;
            if (row < n) {
#pragma unroll
                for (int nn = 0; nn < 4; ++nn) {
                    int col = nn * 16 + cl;
                    if (col < 40)
                        out[(size_t)row * 40 + col] = v[nn] - mx - ls;
                }
            }
        }
    }
}

// ---------------------------------------------------------------------------
extern "C" void kernel_launch(void* const* d_in, const int* in_sizes, int n_in,
                              void* d_out, int out_size, void* d_ws, size_t ws_size,
                              hipStream_t stream)
{
    const float* x       = (const float*)d_in[0];
    const int*   ei      = (const int*)  d_in[1];
    const float* ew      = (const float*)d_in[2];
    const float* w1_rel  = (const float*)d_in[3];
    const float* b1      = (const float*)d_in[4];
    const float* w1_root = (const float*)d_in[5];
    const float* w2_rel  = (const float*)d_in[6];
    const float* b2      = (const float*)d_in[7];
    const float* w2_root = (const float*)d_in[8];
    const float* w_lin   = (const float*)d_in[9];
    const float* b_lin   = (const float*)d_in[10];
    float* out = (float*)d_out;

    const int N = in_sizes[0] / 128;   // 50000
    const int E = in_sizes[2];         // 800000

    auto align = [](char*& p, size_t bytes) {
        char* r = p;
        p += (bytes + 255) & ~(size_t)255;
        return r;
    };
    char* wp = (char*)d_ws;
    __hip_bfloat16* xb     = (__hip_bfloat16*)align(wp, (size_t)N * 128 * 2);
    __hip_bfloat16* agg1b  = (__hip_bfloat16*)align(wp, (size_t)N * 128 * 2);
    __hip_bfloat16* x1b    = (__hip_bfloat16*)align(wp, (size_t)N * 256 * 2);
    __hip_bfloat16* agg2b  = (__hip_bfloat16*)align(wp, (size_t)N * 256 * 2);
    __hip_bfloat16* x2b    = (__hip_bfloat16*)align(wp, (size_t)N * 256 * 2);
    unsigned char*  xb8    = (unsigned char*)align(wp, (size_t)N * 128);
    unsigned char*  x1b8   = (unsigned char*)align(wp, (size_t)N * 256);
    __hip_bfloat16* w1relT  = (__hip_bfloat16*)align(wp, 256 * 128 * 2);
    __hip_bfloat16* w1rootT = (__hip_bfloat16*)align(wp, 256 * 128 * 2);
    __hip_bfloat16* w2relT  = (__hip_bfloat16*)align(wp, 256 * 256 * 2);
    __hip_bfloat16* w2rootT = (__hip_bfloat16*)align(wp, 256 * 256 * 2);
    __hip_bfloat16* wlinT   = (__hip_bfloat16*)align(wp, 2 * 64 * 256 * 2);
    int*   counts  = (int*)align(wp, (size_t)N * 4);
    int*   row_ptr = (int*)align(wp, (size_t)(N + 1) * 4);
    int*   cursor  = (int*)align(wp, (size_t)N * 4);
    int*   bsum    = (int*)align(wp, 256 * 4);
    int*   bpre    = (int*)align(wp, 256 * 4);
    int2*  edges   = (int2*)align(wp, (size_t)E * 8);

    const int eb = (E + 255) / 256;
    const int nb = (N + 255) / 256;   // 196 <= 256

    hipMemsetAsync(counts, 0, (size_t)N * 4, stream);
    const int NX8 = N * 128 / 8;       // 800000
    {
        long long total = (long long)E + NX8 + 229376;
        int blocks = (int)((total + 255) / 256);
        prep_all<<<blocks, 256, 0, stream>>>(
            ei, counts, E, x, xb, xb8, NX8,
            w1_rel, w1_root, w2_rel, w2_root, w_lin,
            w1relT, w1rootT, w2relT, w2rootT, wlinT);
    }
    scan_block_sums<<<nb, 256, 0, stream>>>(counts, bsum, N);
    scan_bsum<<<1, 256, 0, stream>>>(bsum, bpre, nb);
    scan_final<<<nb, 256, 0, stream>>>(counts, bpre, row_ptr, cursor, N, E);
    fill_kernel<<<eb, 256, 0, stream>>>(ei, ew, cursor, edges, E);

    const int gather_blocks = (N * 64 + 255) / 256;
    const int gemm_grid     = ((N + 127) / 128) * 2;
    const int head_grid     = (N + 127) / 128;

    // layer 1
    gather_fp8<128><<<gather_blocks, 256, 0, stream>>>(
        xb8, edges, row_ptr, agg1b, N);
    gemm_mfma<true><<<gemm_grid, 256, 0, stream>>>(
        agg1b, xb, w1relT, w1rootT, b1, x1b, x1b8, N, 128, 128);
    // layer 2
    gather_fp8<256><<<gather_blocks, 256, 0, stream>>>(
        x1b8, edges, row_ptr, agg2b, N);
    gemm_mfma<false><<<gemm_grid, 256, 0, stream>>>(
        agg2b, x1b, w2relT, w2rootT, b2, x2b, nullptr, N, 256, 256);
    // head
    head_mfma<<<head_grid, 256, 0, stream>>>(x1b, x2b, wlinT, b_lin, out, N);
}

// Round 11
// 229.088 us; speedup vs baseline: 1.1902x; 1.0122x over previous
//
#include <hip/hip_runtime.h>
#include <hip/hip_bf16.h>
#include <hip/hip_fp16.h>
#include <math.h>

// ---------------------------------------------------------------------------
// GraphConv GNN, round 10: 4-byte packed edge records (u16 src | f16 weight).
// One node's edge run fits a single 64B line -> 16x fewer dirty lines in the
// CSR fill scatter. Gather unpacks with 1 shfl/edge. Rest as R9.
// ---------------------------------------------------------------------------

typedef __attribute__((ext_vector_type(8))) short short8;
typedef __attribute__((ext_vector_type(4))) float f32x4;

static __device__ __forceinline__ float bf2f(unsigned short u) {
    return __uint_as_float(((unsigned)u) << 16);
}

// ---- fp8 e4m3 helpers -----------------------------------------------------
static __device__ __forceinline__ void fp8x4_to_f32(unsigned u, float* o) {
#if __has_builtin(__builtin_amdgcn_cvt_pk_f32_fp8)
    auto lo = __builtin_amdgcn_cvt_pk_f32_fp8((int)u, false);
    auto hi = __builtin_amdgcn_cvt_pk_f32_fp8((int)u, true);
    o[0] = lo[0]; o[1] = lo[1]; o[2] = hi[0]; o[3] = hi[1];
#else
#pragma unroll
    for (int i = 0; i < 4; ++i) {
        unsigned b = (u >> (8 * i)) & 0xffu;
        unsigned short hb = (unsigned short)(((b & 0x80u) << 8) | ((b & 0x7fu) << 7));
        o[i] = __half2float(__ushort_as_half(hb)) * 256.0f;
    }
#endif
}

static __device__ __forceinline__ unsigned f32_to_fp8(float f) {
    __half h = __float2half(f * 0.00390625f);            // 2^-8
    unsigned short hb = __half_as_ushort(h);
    unsigned mag = hb & 0x7fffu;
    unsigned s = (hb >> 8) & 0x80u;
    unsigned v = (mag + 0x3fu + ((mag >> 7) & 1u)) >> 7; // RNE
    if (v > 0x7eu) v = 0x7eu;                            // clamp below NaN
    return s | v;
}

// ---- CSR scan -------------------------------------------------------------
__global__ __launch_bounds__(256) void scan_block_sums(
    const int* __restrict__ counts, int* __restrict__ bsum, int n)
{
    __shared__ int sh[256];
    int idx = blockIdx.x * 256 + threadIdx.x;
    sh[threadIdx.x] = (idx < n) ? counts[idx] : 0;
    __syncthreads();
#pragma unroll
    for (int off = 128; off; off >>= 1) {
        if (threadIdx.x < off) sh[threadIdx.x] += sh[threadIdx.x + off];
        __syncthreads();
    }
    if (threadIdx.x == 0) bsum[blockIdx.x] = sh[0];
}

__global__ __launch_bounds__(256) void scan_bsum(
    const int* __restrict__ bsum, int* __restrict__ bpre, int nb)
{
    __shared__ int sh[256];
    int t = threadIdx.x;
    int v = (t < nb) ? bsum[t] : 0;
    sh[t] = v;
    __syncthreads();
#pragma unroll
    for (int off = 1; off < 256; off <<= 1) {
        int u = (t >= off) ? sh[t - off] : 0;
        __syncthreads();
        sh[t] += u;
        __syncthreads();
    }
    bpre[t] = sh[t] - v;   // exclusive
}

__global__ __launch_bounds__(256) void scan_final(
    const int* __restrict__ counts, const int* __restrict__ bpre,
    int* __restrict__ row_ptr, int* __restrict__ cursor, int n, int Etot)
{
    __shared__ int sh[256];
    int t = threadIdx.x;
    int idx = blockIdx.x * 256 + t;
    int v = (idx < n) ? counts[idx] : 0;
    sh[t] = v;
    __syncthreads();
#pragma unroll
    for (int off = 1; off < 256; off <<= 1) {
        int u = (t >= off) ? sh[t - off] : 0;
        __syncthreads();
        sh[t] += u;
        __syncthreads();
    }
    if (idx < n) {
        int val = bpre[blockIdx.x] + sh[t] - v;
        row_ptr[idx] = val;
        cursor[idx]  = val;
    }
    if (idx == 0) row_ptr[n] = Etot;
}

// ---- fill: 4B packed edge record (u16 src | f16 weight) -------------------
__global__ __launch_bounds__(256) void fill_kernel(
    const int* __restrict__ ei, const float* __restrict__ ew,
    int* __restrict__ cursor, unsigned* __restrict__ edges, int E)
{
    int e = blockIdx.x * 256 + threadIdx.x;
    if (e >= E) return;
    int d = ei[E + e];
    int p = atomicAdd(&cursor[d], 1);
    unsigned short w16 = __half_as_ushort(__float2half(ew[e]));
    edges[p] = ((unsigned)w16 << 16) | (unsigned)ei[e];   // src < 65536
}

// ---- fused prep: count atomics + x->bf16+fp8 + weight transposes ----------
__global__ __launch_bounds__(256) void prep_all(
    const int* __restrict__ ei, int* __restrict__ counts, int E,
    const float* __restrict__ x, __hip_bfloat16* __restrict__ xb,
    unsigned char* __restrict__ xb8, int NX8,
    const float* __restrict__ w1_rel, const float* __restrict__ w1_root,
    const float* __restrict__ w2_rel, const float* __restrict__ w2_root,
    const float* __restrict__ w_lin,
    __hip_bfloat16* __restrict__ w1relT, __hip_bfloat16* __restrict__ w1rootT,
    __hip_bfloat16* __restrict__ w2relT, __hip_bfloat16* __restrict__ w2rootT,
    __hip_bfloat16* __restrict__ wlinT)
{
    int idx = blockIdx.x * 256 + threadIdx.x;
    if (idx < E) {
        atomicAdd(&counts[ei[E + idx]], 1);
        return;
    }
    idx -= E;
    if (idx < NX8) {   // x -> bf16 + fp8, 8 elems/thread
        float4 a = *(const float4*)&x[(size_t)idx * 8];
        float4 b = *(const float4*)&x[(size_t)idx * 8 + 4];
        float f[8] = { a.x, a.y, a.z, a.w, b.x, b.y, b.z, b.w };
        __hip_bfloat16 o[8];
#pragma unroll
        for (int i = 0; i < 8; ++i) o[i] = __float2bfloat16(f[i]);
        *(short8*)&xb[(size_t)idx * 8] = *(short8*)o;
        unsigned p0 = 0, p1 = 0;
#pragma unroll
        for (int i = 0; i < 4; ++i) p0 |= f32_to_fp8(f[i]) << (8 * i);
#pragma unroll
        for (int i = 0; i < 4; ++i) p1 |= f32_to_fp8(f[4 + i]) << (8 * i);
        *(uint2*)&xb8[(size_t)idx * 8] = make_uint2(p0, p1);
        return;
    }
    idx -= NX8;
    if (idx < 65536) {                       // w1_rel/w1_root [128,256] -> [256,128]
        const float* src = (idx < 32768) ? w1_rel : w1_root;
        __hip_bfloat16* dst = (idx < 32768) ? w1relT : w1rootT;
        int i = idx & 32767;
        int k = i >> 8, c = i & 255;
        dst[c * 128 + k] = __float2bfloat16(src[i]);
    } else if (idx < 196608) {               // w2_rel/w2_root [256,256]^T
        int j = idx - 65536;
        const float* src = (j < 65536) ? w2_rel : w2_root;
        __hip_bfloat16* dst = (j < 65536) ? w2relT : w2rootT;
        int i = j & 65535;
        int k = i >> 8, c = i & 255;
        dst[c * 256 + k] = __float2bfloat16(src[i]);
    } else if (idx < 229376) {               // w_lin [512,40] -> [2][64][256]
        int i = idx - 196608;
        int seg = i >> 14, c = (i >> 8) & 63, k = i & 255;
        float v = (c < 40) ? w_lin[(size_t)(seg * 256 + k) * 40 + c] : 0.f;
        wlinT[i] = __float2bfloat16(v);
    }
}

// ---- gather (fp8 table, 4B edges): agg[v,:] = sum_e w_e * feat8[src_e,:] --
template <int C>
__global__ __launch_bounds__(256) void gather_fp8(
    const unsigned char* __restrict__ feat8,
    const unsigned* __restrict__ edges,
    const int*  __restrict__ rp,
    __hip_bfloat16* __restrict__ agg, int n)
{
    const int node = (blockIdx.x * 256 + threadIdx.x) >> 6;
    const int lane = threadIdx.x & 63;
    if (node >= n) return;
    const int beg = __builtin_amdgcn_readfirstlane(rp[node]);
    const int end = __builtin_amdgcn_readfirstlane(rp[node + 1]);

    constexpr int EPW = (C == 128) ? 8 : 4;       // edge slots per step
    constexpr int LPR = 64 / EPW;                 // lanes per row
    const int es = lane / LPR;
    const int ch = lane % LPR;
    const unsigned coff = (unsigned)ch * 16;      // byte offset of 16-elem chunk

    float acc[16] = {};

    auto accum16 = [&](uint4 u, float w) {
        unsigned uu[4] = { u.x, u.y, u.z, u.w };
#pragma unroll
        for (int q = 0; q < 4; ++q) {
            float f[4];
            fp8x4_to_f32(uu[q], f);
#pragma unroll
            for (int i = 0; i < 4; ++i)
                acc[q * 4 + i] = fmaf(f[i], w, acc[q * 4 + i]);
        }
    };

    auto unpack_w = [](unsigned p) {
        return __half2float(__ushort_as_half((unsigned short)(p >> 16)));
    };

    for (int base = beg; base < end; base += 64) {
        const int m = min(64, end - base);
        // one coalesced 4B edge load; pad lanes carry weight 0 (shfl-safe)
        unsigned ev = edges[base + ((lane < m) ? lane : (m - 1))];
        if (lane >= m) ev &= 0xffffu;

        int s = 0;
        for (; s + 2 * EPW <= m; s += 2 * EPW) {
            int j0 = s + es, j1 = j0 + EPW;
            unsigned p0 = (unsigned)__shfl((int)ev, j0, 64);
            unsigned p1 = (unsigned)__shfl((int)ev, j1, 64);
            uint4 u0 = *(const uint4*)(feat8 + (size_t)(p0 & 0xffffu) * C + coff);
            uint4 u1 = *(const uint4*)(feat8 + (size_t)(p1 & 0xffffu) * C + coff);
            accum16(u0, unpack_w(p0));
            accum16(u1, unpack_w(p1));
        }
        for (; s < m; s += EPW) {
            int j = min(s + es, 63);
            unsigned p = (unsigned)__shfl((int)ev, j, 64);
            uint4 u = *(const uint4*)(feat8 + (size_t)(p & 0xffffu) * C + coff);
            accum16(u, unpack_w(p));
        }
    }

#pragma unroll
    for (int k = 0; k < 16; ++k) {
        if constexpr (C == 128) {
            acc[k] += __shfl_xor(acc[k], 8, 64);
            acc[k] += __shfl_xor(acc[k], 16, 64);
            acc[k] += __shfl_xor(acc[k], 32, 64);
        } else {
            acc[k] += __shfl_xor(acc[k], 16, 64);
            acc[k] += __shfl_xor(acc[k], 32, 64);
        }
    }
    if (es == 0) {
        __hip_bfloat16 o[16];
#pragma unroll
        for (int k = 0; k < 16; ++k) o[k] = __float2bfloat16(acc[k]);
        __hip_bfloat16* op = agg + (size_t)node * C + ch * 16;
        *(short8*)op       = *(short8*)o;
        *(short8*)(op + 8) = *(short8*)(o + 8);
    }
}

// ---- MFMA GEMM: C = relu(A0@W0 + A1@W1 + bias), NC=256, bf16 in/out -------
// 2-phase double-buffered K-pipeline; LDS-staged coalesced epilogue.
template <bool WRITE_FP8>
__global__ __launch_bounds__(256) void gemm_mfma(
    const __hip_bfloat16* __restrict__ A0, const __hip_bfloat16* __restrict__ A1,
    const __hip_bfloat16* __restrict__ W0T, const __hip_bfloat16* __restrict__ W1T,
    const float* __restrict__ bias,
    __hip_bfloat16* __restrict__ Cmat,
    unsigned char* __restrict__ Cfp8,
    int n, int K0, int K1)
{
    __shared__ __hip_bfloat16 Asl[2][128 * 64];   // 32 KB
    __shared__ __hip_bfloat16 Bsl[2][128 * 64];   // 32 KB
    const int bm = blockIdx.x >> 1;
    const int bn = blockIdx.x & 1;
    const int row0 = bm * 128, col0 = bn * 128;
    const int t = threadIdx.x, lane = t & 63, wid = t >> 6;
    const int wr = wid >> 1, wc = wid & 1;

    const int S0 = K0 >> 6;                 // steps in segment 0
    const int S  = S0 + (K1 >> 6);          // total K-steps

    auto stage = [&](int buf, int s) {
        const __hip_bfloat16* A;
        const __hip_bfloat16* WT;
        int K, k0;
        if (s < S0) { A = A0; WT = W0T; K = K0; k0 = s << 6; }
        else        { A = A1; WT = W1T; K = K1; k0 = (s - S0) << 6; }
#pragma unroll
        for (int i = 0; i < 4; ++i) {
            int idx = i * 256 + t;
            int r = idx >> 3, c = idx & 7;
            int gr = row0 + r; if (gr >= n) gr = n - 1;
            const __hip_bfloat16* srcA =
                A + (size_t)gr * K + k0 + ((c ^ (r & 7)) << 3);
            __builtin_amdgcn_global_load_lds(
                (const __attribute__((address_space(1))) void*)srcA,
                (__attribute__((address_space(3))) void*)&Asl[buf][idx * 8], 16, 0, 0);
            const __hip_bfloat16* srcB =
                WT + (size_t)(col0 + r) * K + k0 + ((c ^ (r & 7)) << 3);
            __builtin_amdgcn_global_load_lds(
                (const __attribute__((address_space(1))) void*)srcB,
                (__attribute__((address_space(3))) void*)&Bsl[buf][idx * 8], 16, 0, 0);
        }
    };

    f32x4 acc[4][4] = {};

    stage(0, 0);
    __syncthreads();                         // drains step-0 loads

    for (int s = 0; s < S; ++s) {
        const int buf = s & 1;
        if (s + 1 < S) stage(buf ^ 1, s + 1);   // prefetch overlaps MFMA below
#pragma unroll
        for (int kh = 0; kh < 2; ++kh) {
            const int cchunk = kh * 4 + (lane >> 4);
            short8 af[4], bfr[4];
#pragma unroll
            for (int m = 0; m < 4; ++m) {
                int r = wr * 64 + m * 16 + (lane & 15);
                af[m] = *(const short8*)&Asl[buf][r * 64 + ((cchunk ^ (r & 7)) << 3)];
            }
#pragma unroll
            for (int nn = 0; nn < 4; ++nn) {
                int r = wc * 64 + nn * 16 + (lane & 15);
                bfr[nn] = *(const short8*)&Bsl[buf][r * 64 + ((cchunk ^ (r & 7)) << 3)];
            }
#pragma unroll
            for (int m = 0; m < 4; ++m)
#pragma unroll
                for (int nn = 0; nn < 4; ++nn)
                    acc[m][nn] = __builtin_amdgcn_mfma_f32_16x16x32_bf16(
                        af[m], bfr[nn], acc[m][nn], 0, 0, 0);
        }
        __syncthreads();   // drains prefetch + guards buffer reuse
    }

    // ---- epilogue: bias+relu -> LDS tile -> coalesced global writes -------
    __hip_bfloat16* Csh = &Asl[0][0];        // 128x128 bf16 = 32 KB
#pragma unroll
    for (int nn = 0; nn < 4; ++nn) {
        int lcol = wc * 64 + nn * 16 + (lane & 15);
        float b = bias[col0 + lcol];
#pragma unroll
        for (int m = 0; m < 4; ++m) {
#pragma unroll
            for (int rg = 0; rg < 4; ++rg) {
                int lrow = wr * 64 + m * 16 + ((lane >> 4) * 4) + rg;
                float v = fmaxf(acc[m][nn][rg] + b, 0.f);
                Csh[lrow * 128 + lcol] = __float2bfloat16(v);
            }
        }
    }
    __syncthreads();

#pragma unroll
    for (int it = 0; it < 8; ++it) {
        int idx = it * 256 + t;
        int r = idx >> 4, c16 = idx & 15;
        if (row0 + r < n)
            *(short8*)(Cmat + (size_t)(row0 + r) * 256 + col0 + c16 * 8) =
                *(const short8*)&Csh[r * 128 + c16 * 8];
    }
    if constexpr (WRITE_FP8) {
#pragma unroll
        for (int it = 0; it < 4; ++it) {
            int idx = it * 256 + t;
            int r = idx >> 3, c16 = idx & 7;
            if (row0 + r < n) {
                const __hip_bfloat16* src = &Csh[r * 128 + c16 * 16];
                unsigned w[4];
#pragma unroll
                for (int q = 0; q < 4; ++q) {
                    unsigned p = 0;
#pragma unroll
                    for (int i = 0; i < 4; ++i)
                        p |= f32_to_fp8(__bfloat162float(src[q * 4 + i])) << (8 * i);
                    w[q] = p;
                }
                *(uint4*)(Cfp8 + (size_t)(row0 + r) * 256 + col0 + c16 * 16) =
                    make_uint4(w[0], w[1], w[2], w[3]);
            }
        }
    }
}

// ---- head: out = log_softmax([x1|x2] @ w_lin + b_lin), MFMA fused ---------
__global__ __launch_bounds__(256) void head_mfma(
    const __hip_bfloat16* __restrict__ X1, const __hip_bfloat16* __restrict__ X2,
    const __hip_bfloat16* __restrict__ WLT,   // [2][64][256]
    const float* __restrict__ b_lin,
    float* __restrict__ out, int n)
{
    __shared__ __hip_bfloat16 Asl[128 * 64];
    __shared__ __hip_bfloat16 Bsl[64 * 64];
    const int row0 = blockIdx.x * 128;
    const int t = threadIdx.x, lane = t & 63, wid = t >> 6;

    f32x4 acc[2][4] = {};

    for (int seg = 0; seg < 2; ++seg) {
        const __hip_bfloat16* A  = seg ? X2 : X1;
        const __hip_bfloat16* WT = WLT + seg * 64 * 256;
        for (int k0 = 0; k0 < 256; k0 += 64) {
#pragma unroll
            for (int i = 0; i < 4; ++i) {
                int idx = i * 256 + t;
                int r = idx >> 3, c = idx & 7;
                int gr = row0 + r; if (gr >= n) gr = n - 1;
                const __hip_bfloat16* srcA =
                    A + (size_t)gr * 256 + k0 + ((c ^ (r & 7)) << 3);
                __builtin_amdgcn_global_load_lds(
                    (const __attribute__((address_space(1))) void*)srcA,
                    (__attribute__((address_space(3))) void*)&Asl[idx * 8], 16, 0, 0);
            }
#pragma unroll
            for (int i = 0; i < 2; ++i) {
                int idx = i * 256 + t;
                int r = idx >> 3, c = idx & 7;
                const __hip_bfloat16* srcB =
                    WT + (size_t)r * 256 + k0 + ((c ^ (r & 7)) << 3);
                __builtin_amdgcn_global_load_lds(
                    (const __attribute__((address_space(1))) void*)srcB,
                    (__attribute__((address_space(3))) void*)&Bsl[idx * 8], 16, 0, 0);
            }
            __syncthreads();
#pragma unroll
            for (int kh = 0; kh < 2; ++kh) {
                const int cchunk = kh * 4 + (lane >> 4);
                short8 af[2], bfr[4];
#pragma unroll
                for (int m = 0; m < 2; ++m) {
                    int r = wid * 32 + m * 16 + (lane & 15);
                    af[m] = *(const short8*)&Asl[r * 64 + ((cchunk ^ (r & 7)) << 3)];
                }
#pragma unroll
                for (int nn = 0; nn < 4; ++nn) {
                    int r = nn * 16 + (lane & 15);
                    bfr[nn] = *(const short8*)&Bsl[r * 64 + ((cchunk ^ (r & 7)) << 3)];
                }
#pragma unroll
                for (int m = 0; m < 2; ++m)
#pragma unroll
                    for (int nn = 0; nn < 4; ++nn)
                        acc[m][nn] = __builtin_amdgcn_mfma_f32_16x16x32_bf16(
                            af[m], bfr[nn], acc[m][nn], 0, 0, 0);
            }
            __syncthreads();
        }
    }

    const int cl = lane & 15;
    float bb[4];
#pragma unroll
    for (int nn = 0; nn < 4; ++nn) {
        int col = nn * 16 + cl;
        bb[nn] = (col < 40) ? b_lin[col] : 0.f;
    }
#pragma unroll
    for (int m = 0; m < 2; ++m) {
#pragma unroll
        for (int rg = 0; rg < 4; ++rg) {
            float v[4];
            float mx = -1e30f;
#pragma unroll
            for (int nn = 0; nn < 4; ++nn) {
                int col = nn * 16 + cl;
                v[nn] = acc[m][nn][rg] + bb[nn];
                if (col < 40) mx = fmaxf(mx, v[nn]);
            }
#pragma unroll
            for (int off = 1; off < 16; off <<= 1)
                mx = fmaxf(mx, __shfl_xor(mx, off, 64));
            float s = 0.f;
#pragma unroll
            for (int nn = 0; nn < 4; ++nn) {
                int col = nn * 16 + cl;
                if (col < 40) s += expf(v[nn] - mx);
            }
#pragma unroll
            for (int off = 1; off < 16; off <<= 1)
                s += __shfl_xor(s, off, 64);
            float ls = logf(s);
            int row = row0 + wid * 32 + m * 16 + ((lane >> 4) * 4) + rg;
            if (row < n) {
#pragma unroll
                for (int nn = 0; nn < 4; ++nn) {
                    int col = nn * 16 + cl;
                    if (col < 40)
                        out[(size_t)row * 40 + col] = v[nn] - mx - ls;
                }
            }
        }
    }
}

// ---------------------------------------------------------------------------
extern "C" void kernel_launch(void* const* d_in, const int* in_sizes, int n_in,
                              void* d_out, int out_size, void* d_ws, size_t ws_size,
                              hipStream_t stream)
{
    const float* x       = (const float*)d_in[0];
    const int*   ei      = (const int*)  d_in[1];
    const float* ew      = (const float*)d_in[2];
    const float* w1_rel  = (const float*)d_in[3];
    const float* b1      = (const float*)d_in[4];
    const float* w1_root = (const float*)d_in[5];
    const float* w2_rel  = (const float*)d_in[6];
    const float* b2      = (const float*)d_in[7];
    const float* w2_root = (const float*)d_in[8];
    const float* w_lin   = (const float*)d_in[9];
    const float* b_lin   = (const float*)d_in[10];
    float* out = (float*)d_out;

    const int N = in_sizes[0] / 128;   // 50000 (< 65536: u16 src pack valid)
    const int E = in_sizes[2];         // 800000

    auto align = [](char*& p, size_t bytes) {
        char* r = p;
        p += (bytes + 255) & ~(size_t)255;
        return r;
    };
    char* wp = (char*)d_ws;
    __hip_bfloat16* xb     = (__hip_bfloat16*)align(wp, (size_t)N * 128 * 2);
    __hip_bfloat16* agg1b  = (__hip_bfloat16*)align(wp, (size_t)N * 128 * 2);
    __hip_bfloat16* x1b    = (__hip_bfloat16*)align(wp, (size_t)N * 256 * 2);
    __hip_bfloat16* agg2b  = (__hip_bfloat16*)align(wp, (size_t)N * 256 * 2);
    __hip_bfloat16* x2b    = (__hip_bfloat16*)align(wp, (size_t)N * 256 * 2);
    unsigned char*  xb8    = (unsigned char*)align(wp, (size_t)N * 128);
    unsigned char*  x1b8   = (unsigned char*)align(wp, (size_t)N * 256);
    __hip_bfloat16* w1relT  = (__hip_bfloat16*)align(wp, 256 * 128 * 2);
    __hip_bfloat16* w1rootT = (__hip_bfloat16*)align(wp, 256 * 128 * 2);
    __hip_bfloat16* w2relT  = (__hip_bfloat16*)align(wp, 256 * 256 * 2);
    __hip_bfloat16* w2rootT = (__hip_bfloat16*)align(wp, 256 * 256 * 2);
    __hip_bfloat16* wlinT   = (__hip_bfloat16*)align(wp, 2 * 64 * 256 * 2);
    int*      counts  = (int*)align(wp, (size_t)N * 4);
    int*      row_ptr = (int*)align(wp, (size_t)(N + 1) * 4);
    int*      cursor  = (int*)align(wp, (size_t)N * 4);
    int*      bsum    = (int*)align(wp, 256 * 4);
    int*      bpre    = (int*)align(wp, 256 * 4);
    unsigned* edges   = (unsigned*)align(wp, (size_t)E * 4);

    const int eb = (E + 255) / 256;
    const int nb = (N + 255) / 256;   // 196 <= 256

    hipMemsetAsync(counts, 0, (size_t)N * 4, stream);
    const int NX8 = N * 128 / 8;       // 800000
    {
        long long total = (long long)E + NX8 + 229376;
        int blocks = (int)((total + 255) / 256);
        prep_all<<<blocks, 256, 0, stream>>>(
            ei, counts, E, x, xb, xb8, NX8,
            w1_rel, w1_root, w2_rel, w2_root, w_lin,
            w1relT, w1rootT, w2relT, w2rootT, wlinT);
    }
    scan_block_sums<<<nb, 256, 0, stream>>>(counts, bsum, N);
    scan_bsum<<<1, 256, 0, stream>>>(bsum, bpre, nb);
    scan_final<<<nb, 256, 0, stream>>>(counts, bpre, row_ptr, cursor, N, E);
    fill_kernel<<<eb, 256, 0, stream>>>(ei, ew, cursor, edges, E);

    const int gather_blocks = (N * 64 + 255) / 256;
    const int gemm_grid     = ((N + 127) / 128) * 2;
    const int head_grid     = (N + 127) / 128;

    // layer 1
    gather_fp8<128><<<gather_blocks, 256, 0, stream>>>(
        xb8, edges, row_ptr, agg1b, N);
    gemm_mfma<true><<<gemm_grid, 256, 0, stream>>>(
        agg1b, xb, w1relT, w1rootT, b1, x1b, x1b8, N, 128, 128);
    // layer 2
    gather_fp8<256><<<gather_blocks, 256, 0, stream>>>(
        x1b8, edges, row_ptr, agg2b, N);
    gemm_mfma<false><<<gemm_grid, 256, 0, stream>>>(
        agg2b, x1b, w2relT, w2rootT, b2, x2b, nullptr, N, 256, 256);
    // head
    head_mfma<<<head_grid, 256, 0, stream>>>(x1b, x2b, wlinT, b_lin, out, N);
}

// Round 12
// 208.018 us; speedup vs baseline: 1.3108x; 1.1013x over previous
//
#include <hip/hip_runtime.h>
#include <hip/hip_bf16.h>
#include <hip/hip_fp16.h>
#include <math.h>

// ---------------------------------------------------------------------------
// GraphConv GNN, round 11: 2-pass bucket-partitioned CSR fill.
// Pass 1 partitions edges into 256-node buckets (LDS histogram + reserved
// contiguous runs -> ~80B coalesced writes). Pass 2: one block per bucket,
// LDS node-cursors, final scatter confined to the bucket's own region
// (single-XCD -> L2 merges; kills the 54MB cross-XCD writeback amp).
// ---------------------------------------------------------------------------

typedef __attribute__((ext_vector_type(8))) short short8;
typedef __attribute__((ext_vector_type(4))) float f32x4;

static __device__ __forceinline__ float bf2f(unsigned short u) {
    return __uint_as_float(((unsigned)u) << 16);
}

// ---- fp8 e4m3 helpers -----------------------------------------------------
static __device__ __forceinline__ void fp8x4_to_f32(unsigned u, float* o) {
#if __has_builtin(__builtin_amdgcn_cvt_pk_f32_fp8)
    auto lo = __builtin_amdgcn_cvt_pk_f32_fp8((int)u, false);
    auto hi = __builtin_amdgcn_cvt_pk_f32_fp8((int)u, true);
    o[0] = lo[0]; o[1] = lo[1]; o[2] = hi[0]; o[3] = hi[1];
#else
#pragma unroll
    for (int i = 0; i < 4; ++i) {
        unsigned b = (u >> (8 * i)) & 0xffu;
        unsigned short hb = (unsigned short)(((b & 0x80u) << 8) | ((b & 0x7fu) << 7));
        o[i] = __half2float(__ushort_as_half(hb)) * 256.0f;
    }
#endif
}

static __device__ __forceinline__ unsigned f32_to_fp8(float f) {
    __half h = __float2half(f * 0.00390625f);            // 2^-8
    unsigned short hb = __half_as_ushort(h);
    unsigned mag = hb & 0x7fffu;
    unsigned s = (hb >> 8) & 0x80u;
    unsigned v = (mag + 0x3fu + ((mag >> 7) & 1u)) >> 7; // RNE
    if (v > 0x7eu) v = 0x7eu;                            // clamp below NaN
    return s | v;
}

// ---- CSR scan -------------------------------------------------------------
__global__ __launch_bounds__(256) void scan_block_sums(
    const int* __restrict__ counts, int* __restrict__ bsum, int n)
{
    __shared__ int sh[256];
    int idx = blockIdx.x * 256 + threadIdx.x;
    sh[threadIdx.x] = (idx < n) ? counts[idx] : 0;
    __syncthreads();
#pragma unroll
    for (int off = 128; off; off >>= 1) {
        if (threadIdx.x < off) sh[threadIdx.x] += sh[threadIdx.x + off];
        __syncthreads();
    }
    if (threadIdx.x == 0) bsum[blockIdx.x] = sh[0];
}

// also seeds bucket_cursor (pass-1 reservation cursors)
__global__ __launch_bounds__(256) void scan_bsum(
    const int* __restrict__ bsum, int* __restrict__ bpre,
    int* __restrict__ bucket_cursor, int nb)
{
    __shared__ int sh[256];
    int t = threadIdx.x;
    int v = (t < nb) ? bsum[t] : 0;
    sh[t] = v;
    __syncthreads();
#pragma unroll
    for (int off = 1; off < 256; off <<= 1) {
        int u = (t >= off) ? sh[t - off] : 0;
        __syncthreads();
        sh[t] += u;
        __syncthreads();
    }
    bpre[t]          = sh[t] - v;   // exclusive
    bucket_cursor[t] = sh[t] - v;
}

__global__ __launch_bounds__(256) void scan_final(
    const int* __restrict__ counts, const int* __restrict__ bpre,
    int* __restrict__ row_ptr, int n, int Etot)
{
    __shared__ int sh[256];
    int t = threadIdx.x;
    int idx = blockIdx.x * 256 + t;
    int v = (idx < n) ? counts[idx] : 0;
    sh[t] = v;
    __syncthreads();
#pragma unroll
    for (int off = 1; off < 256; off <<= 1) {
        int u = (t >= off) ? sh[t - off] : 0;
        __syncthreads();
        sh[t] += u;
        __syncthreads();
    }
    if (idx < n) row_ptr[idx] = bpre[blockIdx.x] + sh[t] - v;
    if (idx == 0) row_ptr[n] = Etot;
}

// ---- fill pass 1: partition edges into 256-node buckets -------------------
// 256 threads x 8 edges. LDS histogram -> per-bucket reserved runs (~80B)
// written contiguously. part[i] = { w16|src16, dst }.
#define P1_EPB 8
__global__ __launch_bounds__(256) void part_kernel(
    const int* __restrict__ ei, const float* __restrict__ ew,
    int* __restrict__ bucket_cursor, uint2* __restrict__ part, int E)
{
    __shared__ int lhist[256];
    __shared__ int gbase[256];
    const int t = threadIdx.x;
    const int base = blockIdx.x * (256 * P1_EPB);
    lhist[t] = 0;
    __syncthreads();

    int pk[P1_EPB];                     // (bucket<<16) | local_rank, -1 = none
#pragma unroll
    for (int i = 0; i < P1_EPB; ++i) {
        int e = base + i * 256 + t;
        if (e < E) {
            int b = ei[E + e] >> 8;
            int r = atomicAdd(&lhist[b], 1);
            pk[i] = (b << 16) | r;
        } else pk[i] = -1;
    }
    __syncthreads();
    if (lhist[t] > 0) gbase[t] = atomicAdd(&bucket_cursor[t], lhist[t]);
    __syncthreads();
#pragma unroll
    for (int i = 0; i < P1_EPB; ++i) {
        if (pk[i] >= 0) {
            int e = base + i * 256 + t;
            int d = ei[E + e];                       // L1/L2-hot re-read
            unsigned short w16 = __half_as_ushort(__float2half(ew[e]));
            unsigned rec = ((unsigned)w16 << 16) | (unsigned)ei[e];
            int pos = gbase[pk[i] >> 16] + (pk[i] & 0xffff);
            part[pos] = make_uint2(rec, (unsigned)d);
        }
    }
}

// ---- fill pass 2: one block per bucket; LDS cursors; local scatter --------
__global__ __launch_bounds__(256) void fill2_kernel(
    const uint2* __restrict__ part, const int* __restrict__ bpre,
    const int* __restrict__ bsum, const int* __restrict__ row_ptr,
    unsigned* __restrict__ edges, int n)
{
    __shared__ int curs[256];
    const int b = blockIdx.x;
    const int t = threadIdx.x;
    const int node0 = b << 8;
    if (node0 + t < n) curs[t] = row_ptr[node0 + t];
    __syncthreads();
    const int beg = bpre[b];
    const int end = beg + bsum[b];
    for (int i = beg + t; i < end; i += 256) {
        uint2 p = part[i];
        int slot = atomicAdd(&curs[p.y & 255u], 1);
        edges[slot] = p.x;
    }
}

// ---- fused prep: count atomics + x->bf16+fp8 + weight transposes ----------
__global__ __launch_bounds__(256) void prep_all(
    const int* __restrict__ ei, int* __restrict__ counts, int E,
    const float* __restrict__ x, __hip_bfloat16* __restrict__ xb,
    unsigned char* __restrict__ xb8, int NX8,
    const float* __restrict__ w1_rel, const float* __restrict__ w1_root,
    const float* __restrict__ w2_rel, const float* __restrict__ w2_root,
    const float* __restrict__ w_lin,
    __hip_bfloat16* __restrict__ w1relT, __hip_bfloat16* __restrict__ w1rootT,
    __hip_bfloat16* __restrict__ w2relT, __hip_bfloat16* __restrict__ w2rootT,
    __hip_bfloat16* __restrict__ wlinT)
{
    int idx = blockIdx.x * 256 + threadIdx.x;
    if (idx < E) {
        atomicAdd(&counts[ei[E + idx]], 1);
        return;
    }
    idx -= E;
    if (idx < NX8) {   // x -> bf16 + fp8, 8 elems/thread
        float4 a = *(const float4*)&x[(size_t)idx * 8];
        float4 b = *(const float4*)&x[(size_t)idx * 8 + 4];
        float f[8] = { a.x, a.y, a.z, a.w, b.x, b.y, b.z, b.w };
        __hip_bfloat16 o[8];
#pragma unroll
        for (int i = 0; i < 8; ++i) o[i] = __float2bfloat16(f[i]);
        *(short8*)&xb[(size_t)idx * 8] = *(short8*)o;
        unsigned p0 = 0, p1 = 0;
#pragma unroll
        for (int i = 0; i < 4; ++i) p0 |= f32_to_fp8(f[i]) << (8 * i);
#pragma unroll
        for (int i = 0; i < 4; ++i) p1 |= f32_to_fp8(f[4 + i]) << (8 * i);
        *(uint2*)&xb8[(size_t)idx * 8] = make_uint2(p0, p1);
        return;
    }
    idx -= NX8;
    if (idx < 65536) {                       // w1_rel/w1_root [128,256] -> [256,128]
        const float* src = (idx < 32768) ? w1_rel : w1_root;
        __hip_bfloat16* dst = (idx < 32768) ? w1relT : w1rootT;
        int i = idx & 32767;
        int k = i >> 8, c = i & 255;
        dst[c * 128 + k] = __float2bfloat16(src[i]);
    } else if (idx < 196608) {               // w2_rel/w2_root [256,256]^T
        int j = idx - 65536;
        const float* src = (j < 65536) ? w2_rel : w2_root;
        __hip_bfloat16* dst = (j < 65536) ? w2relT : w2rootT;
        int i = j & 65535;
        int k = i >> 8, c = i & 255;
        dst[c * 256 + k] = __float2bfloat16(src[i]);
    } else if (idx < 229376) {               // w_lin [512,40] -> [2][64][256]
        int i = idx - 196608;
        int seg = i >> 14, c = (i >> 8) & 63, k = i & 255;
        float v = (c < 40) ? w_lin[(size_t)(seg * 256 + k) * 40 + c] : 0.f;
        wlinT[i] = __float2bfloat16(v);
    }
}

// ---- gather (fp8 table, 4B edges): agg[v,:] = sum_e w_e * feat8[src_e,:] --
template <int C>
__global__ __launch_bounds__(256) void gather_fp8(
    const unsigned char* __restrict__ feat8,
    const unsigned* __restrict__ edges,
    const int*  __restrict__ rp,
    __hip_bfloat16* __restrict__ agg, int n)
{
    const int node = (blockIdx.x * 256 + threadIdx.x) >> 6;
    const int lane = threadIdx.x & 63;
    if (node >= n) return;
    const int beg = __builtin_amdgcn_readfirstlane(rp[node]);
    const int end = __builtin_amdgcn_readfirstlane(rp[node + 1]);

    constexpr int EPW = (C == 128) ? 8 : 4;       // edge slots per step
    constexpr int LPR = 64 / EPW;                 // lanes per row
    const int es = lane / LPR;
    const int ch = lane % LPR;
    const unsigned coff = (unsigned)ch * 16;      // byte offset of 16-elem chunk

    float acc[16] = {};

    auto accum16 = [&](uint4 u, float w) {
        unsigned uu[4] = { u.x, u.y, u.z, u.w };
#pragma unroll
        for (int q = 0; q < 4; ++q) {
            float f[4];
            fp8x4_to_f32(uu[q], f);
#pragma unroll
            for (int i = 0; i < 4; ++i)
                acc[q * 4 + i] = fmaf(f[i], w, acc[q * 4 + i]);
        }
    };

    auto unpack_w = [](unsigned p) {
        return __half2float(__ushort_as_half((unsigned short)(p >> 16)));
    };

    for (int base = beg; base < end; base += 64) {
        const int m = min(64, end - base);
        unsigned ev = edges[base + ((lane < m) ? lane : (m - 1))];
        if (lane >= m) ev &= 0xffffu;     // zero the weight half (shfl-safe)

        int s = 0;
        for (; s + 2 * EPW <= m; s += 2 * EPW) {
            int j0 = s + es, j1 = j0 + EPW;
            unsigned p0 = (unsigned)__shfl((int)ev, j0, 64);
            unsigned p1 = (unsigned)__shfl((int)ev, j1, 64);
            uint4 u0 = *(const uint4*)(feat8 + (size_t)(p0 & 0xffffu) * C + coff);
            uint4 u1 = *(const uint4*)(feat8 + (size_t)(p1 & 0xffffu) * C + coff);
            accum16(u0, unpack_w(p0));
            accum16(u1, unpack_w(p1));
        }
        for (; s < m; s += EPW) {
            int j = min(s + es, 63);
            unsigned p = (unsigned)__shfl((int)ev, j, 64);
            uint4 u = *(const uint4*)(feat8 + (size_t)(p & 0xffffu) * C + coff);
            accum16(u, unpack_w(p));
        }
    }

#pragma unroll
    for (int k = 0; k < 16; ++k) {
        if constexpr (C == 128) {
            acc[k] += __shfl_xor(acc[k], 8, 64);
            acc[k] += __shfl_xor(acc[k], 16, 64);
            acc[k] += __shfl_xor(acc[k], 32, 64);
        } else {
            acc[k] += __shfl_xor(acc[k], 16, 64);
            acc[k] += __shfl_xor(acc[k], 32, 64);
        }
    }
    if (es == 0) {
        __hip_bfloat16 o[16];
#pragma unroll
        for (int k = 0; k < 16; ++k) o[k] = __float2bfloat16(acc[k]);
        __hip_bfloat16* op = agg + (size_t)node * C + ch * 16;
        *(short8*)op       = *(short8*)o;
        *(short8*)(op + 8) = *(short8*)(o + 8);
    }
}

// ---- MFMA GEMM: C = relu(A0@W0 + A1@W1 + bias), NC=256, bf16 in/out -------
template <bool WRITE_FP8>
__global__ __launch_bounds__(256) void gemm_mfma(
    const __hip_bfloat16* __restrict__ A0, const __hip_bfloat16* __restrict__ A1,
    const __hip_bfloat16* __restrict__ W0T, const __hip_bfloat16* __restrict__ W1T,
    const float* __restrict__ bias,
    __hip_bfloat16* __restrict__ Cmat,
    unsigned char* __restrict__ Cfp8,
    int n, int K0, int K1)
{
    __shared__ __hip_bfloat16 Asl[2][128 * 64];   // 32 KB
    __shared__ __hip_bfloat16 Bsl[2][128 * 64];   // 32 KB
    const int bm = blockIdx.x >> 1;
    const int bn = blockIdx.x & 1;
    const int row0 = bm * 128, col0 = bn * 128;
    const int t = threadIdx.x, lane = t & 63, wid = t >> 6;
    const int wr = wid >> 1, wc = wid & 1;

    const int S0 = K0 >> 6;
    const int S  = S0 + (K1 >> 6);

    auto stage = [&](int buf, int s) {
        const __hip_bfloat16* A;
        const __hip_bfloat16* WT;
        int K, k0;
        if (s < S0) { A = A0; WT = W0T; K = K0; k0 = s << 6; }
        else        { A = A1; WT = W1T; K = K1; k0 = (s - S0) << 6; }
#pragma unroll
        for (int i = 0; i < 4; ++i) {
            int idx = i * 256 + t;
            int r = idx >> 3, c = idx & 7;
            int gr = row0 + r; if (gr >= n) gr = n - 1;
            const __hip_bfloat16* srcA =
                A + (size_t)gr * K + k0 + ((c ^ (r & 7)) << 3);
            __builtin_amdgcn_global_load_lds(
                (const __attribute__((address_space(1))) void*)srcA,
                (__attribute__((address_space(3))) void*)&Asl[buf][idx * 8], 16, 0, 0);
            const __hip_bfloat16* srcB =
                WT + (size_t)(col0 + r) * K + k0 + ((c ^ (r & 7)) << 3);
            __builtin_amdgcn_global_load_lds(
                (const __attribute__((address_space(1))) void*)srcB,
                (__attribute__((address_space(3))) void*)&Bsl[buf][idx * 8], 16, 0, 0);
        }
    };

    f32x4 acc[4][4] = {};

    stage(0, 0);
    __syncthreads();

    for (int s = 0; s < S; ++s) {
        const int buf = s & 1;
        if (s + 1 < S) stage(buf ^ 1, s + 1);
#pragma unroll
        for (int kh = 0; kh < 2; ++kh) {
            const int cchunk = kh * 4 + (lane >> 4);
            short8 af[4], bfr[4];
#pragma unroll
            for (int m = 0; m < 4; ++m) {
                int r = wr * 64 + m * 16 + (lane & 15);
                af[m] = *(const short8*)&Asl[buf][r * 64 + ((cchunk ^ (r & 7)) << 3)];
            }
#pragma unroll
            for (int nn = 0; nn < 4; ++nn) {
                int r = wc * 64 + nn * 16 + (lane & 15);
                bfr[nn] = *(const short8*)&Bsl[buf][r * 64 + ((cchunk ^ (r & 7)) << 3)];
            }
#pragma unroll
            for (int m = 0; m < 4; ++m)
#pragma unroll
                for (int nn = 0; nn < 4; ++nn)
                    acc[m][nn] = __builtin_amdgcn_mfma_f32_16x16x32_bf16(
                        af[m], bfr[nn], acc[m][nn], 0, 0, 0);
        }
        __syncthreads();
    }

    // epilogue: bias+relu -> LDS tile -> coalesced global writes
    __hip_bfloat16* Csh = &Asl[0][0];
#pragma unroll
    for (int nn = 0; nn < 4; ++nn) {
        int lcol = wc * 64 + nn * 16 + (lane & 15);
        float b = bias[col0 + lcol];
#pragma unroll
        for (int m = 0; m < 4; ++m) {
#pragma unroll
            for (int rg = 0; rg < 4; ++rg) {
                int lrow = wr * 64 + m * 16 + ((lane >> 4) * 4) + rg;
                float v = fmaxf(acc[m][nn][rg] + b, 0.f);
                Csh[lrow * 128 + lcol] = __float2bfloat16(v);
            }
        }
    }
    __syncthreads();

#pragma unroll
    for (int it = 0; it < 8; ++it) {
        int idx = it * 256 + t;
        int r = idx >> 4, c16 = idx & 15;
        if (row0 + r < n)
            *(short8*)(Cmat + (size_t)(row0 + r) * 256 + col0 + c16 * 8) =
                *(const short8*)&Csh[r * 128 + c16 * 8];
    }
    if constexpr (WRITE_FP8) {
#pragma unroll
        for (int it = 0; it < 4; ++it) {
            int idx = it * 256 + t;
            int r = idx >> 3, c16 = idx & 7;
            if (row0 + r < n) {
                const __hip_bfloat16* src = &Csh[r * 128 + c16 * 16];
                unsigned w[4];
#pragma unroll
                for (int q = 0; q < 4; ++q) {
                    unsigned p = 0;
#pragma unroll
                    for (int i = 0; i < 4; ++i)
                        p |= f32_to_fp8(__bfloat162float(src[q * 4 + i])) << (8 * i);
                    w[q] = p;
                }
                *(uint4*)(Cfp8 + (size_t)(row0 + r) * 256 + col0 + c16 * 16) =
                    make_uint4(w[0], w[1], w[2], w[3]);
            }
        }
    }
}

// ---- head: out = log_softmax([x1|x2] @ w_lin + b_lin), MFMA fused ---------
__global__ __launch_bounds__(256) void head_mfma(
    const __hip_bfloat16* __restrict__ X1, const __hip_bfloat16* __restrict__ X2,
    const __hip_bfloat16* __restrict__ WLT,   // [2][64][256]
    const float* __restrict__ b_lin,
    float* __restrict__ out, int n)
{
    __shared__ __hip_bfloat16 Asl[128 * 64];
    __shared__ __hip_bfloat16 Bsl[64 * 64];
    const int row0 = blockIdx.x * 128;
    const int t = threadIdx.x, lane = t & 63, wid = t >> 6;

    f32x4 acc[2][4] = {};

    for (int seg = 0; seg < 2; ++seg) {
        const __hip_bfloat16* A  = seg ? X2 : X1;
        const __hip_bfloat16* WT = WLT + seg * 64 * 256;
        for (int k0 = 0; k0 < 256; k0 += 64) {
#pragma unroll
            for (int i = 0; i < 4; ++i) {
                int idx = i * 256 + t;
                int r = idx >> 3, c = idx & 7;
                int gr = row0 + r; if (gr >= n) gr = n - 1;
                const __hip_bfloat16* srcA =
                    A + (size_t)gr * 256 + k0 + ((c ^ (r & 7)) << 3);
                __builtin_amdgcn_global_load_lds(
                    (const __attribute__((address_space(1))) void*)srcA,
                    (__attribute__((address_space(3))) void*)&Asl[idx * 8], 16, 0, 0);
            }
#pragma unroll
            for (int i = 0; i < 2; ++i) {
                int idx = i * 256 + t;
                int r = idx >> 3, c = idx & 7;
                const __hip_bfloat16* srcB =
                    WT + (size_t)r * 256 + k0 + ((c ^ (r & 7)) << 3);
                __builtin_amdgcn_global_load_lds(
                    (const __attribute__((address_space(1))) void*)srcB,
                    (__attribute__((address_space(3))) void*)&Bsl[idx * 8], 16, 0, 0);
            }
            __syncthreads();
#pragma unroll
            for (int kh = 0; kh < 2; ++kh) {
                const int cchunk = kh * 4 + (lane >> 4);
                short8 af[2], bfr[4];
#pragma unroll
                for (int m = 0; m < 2; ++m) {
                    int r = wid * 32 + m * 16 + (lane & 15);
                    af[m] = *(const short8*)&Asl[r * 64 + ((cchunk ^ (r & 7)) << 3)];
                }
#pragma unroll
                for (int nn = 0; nn < 4; ++nn) {
                    int r = nn * 16 + (lane & 15);
                    bfr[nn] = *(const short8*)&Bsl[r * 64 + ((cchunk ^ (r & 7)) << 3)];
                }
#pragma unroll
                for (int m = 0; m < 2; ++m)
#pragma unroll
                    for (int nn = 0; nn < 4; ++nn)
                        acc[m][nn] = __builtin_amdgcn_mfma_f32_16x16x32_bf16(
                            af[m], bfr[nn], acc[m][nn], 0, 0, 0);
            }
            __syncthreads();
        }
    }

    const int cl = lane & 15;
    float bb[4];
#pragma unroll
    for (int nn = 0; nn < 4; ++nn) {
        int col = nn * 16 + cl;
        bb[nn] = (col < 40) ? b_lin[col] : 0.f;
    }
#pragma unroll
    for (int m = 0; m < 2; ++m) {
#pragma unroll
        for (int rg = 0; rg < 4; ++rg) {
            float v[4];
            float mx = -1e30f;
#pragma unroll
            for (int nn = 0; nn < 4; ++nn) {
                int col = nn * 16 + cl;
                v[nn] = acc[m][nn][rg] + bb[nn];
                if (col < 40) mx = fmaxf(mx, v[nn]);
            }
#pragma unroll
            for (int off = 1; off < 16; off <<= 1)
                mx = fmaxf(mx, __shfl_xor(mx, off, 64));
            float s = 0.f;
#pragma unroll
            for (int nn = 0; nn < 4; ++nn) {
                int col = nn * 16 + cl;
                if (col < 40) s += expf(v[nn] - mx);
            }
#pragma unroll
            for (int off = 1; off < 16; off <<= 1)
                s += __shfl_xor(s, off, 64);
            float ls = logf(s);
            int row = row0 + wid * 32 + m * 16 + ((lane >> 4) * 4) + rg;
            if (row < n) {
#pragma unroll
                for (int nn = 0; nn < 4; ++nn) {
                    int col = nn * 16 + cl;
                    if (col < 40)
                        out[(size_t)row * 40 + col] = v[nn] - mx - ls;
                }
            }
        }
    }
}

// ---------------------------------------------------------------------------
extern "C" void kernel_launch(void* const* d_in, const int* in_sizes, int n_in,
                              void* d_out, int out_size, void* d_ws, size_t ws_size,
                              hipStream_t stream)
{
    const float* x       = (const float*)d_in[0];
    const int*   ei      = (const int*)  d_in[1];
    const float* ew      = (const float*)d_in[2];
    const float* w1_rel  = (const float*)d_in[3];
    const float* b1      = (const float*)d_in[4];
    const float* w1_root = (const float*)d_in[5];
    const float* w2_rel  = (const float*)d_in[6];
    const float* b2      = (const float*)d_in[7];
    const float* w2_root = (const float*)d_in[8];
    const float* w_lin   = (const float*)d_in[9];
    const float* b_lin   = (const float*)d_in[10];
    float* out = (float*)d_out;

    const int N = in_sizes[0] / 128;   // 50000 (< 65536: u16 src pack valid)
    const int E = in_sizes[2];         // 800000

    auto align = [](char*& p, size_t bytes) {
        char* r = p;
        p += (bytes + 255) & ~(size_t)255;
        return r;
    };
    char* wp = (char*)d_ws;
    __hip_bfloat16* xb     = (__hip_bfloat16*)align(wp, (size_t)N * 128 * 2);
    __hip_bfloat16* agg1b  = (__hip_bfloat16*)align(wp, (size_t)N * 128 * 2);
    __hip_bfloat16* x1b    = (__hip_bfloat16*)align(wp, (size_t)N * 256 * 2);
    __hip_bfloat16* agg2b  = (__hip_bfloat16*)align(wp, (size_t)N * 256 * 2);
    __hip_bfloat16* x2b    = (__hip_bfloat16*)align(wp, (size_t)N * 256 * 2);
    unsigned char*  xb8    = (unsigned char*)align(wp, (size_t)N * 128);
    unsigned char*  x1b8   = (unsigned char*)align(wp, (size_t)N * 256);
    __hip_bfloat16* w1relT  = (__hip_bfloat16*)align(wp, 256 * 128 * 2);
    __hip_bfloat16* w1rootT = (__hip_bfloat16*)align(wp, 256 * 128 * 2);
    __hip_bfloat16* w2relT  = (__hip_bfloat16*)align(wp, 256 * 256 * 2);
    __hip_bfloat16* w2rootT = (__hip_bfloat16*)align(wp, 256 * 256 * 2);
    __hip_bfloat16* wlinT   = (__hip_bfloat16*)align(wp, 2 * 64 * 256 * 2);
    int*      counts        = (int*)align(wp, (size_t)N * 4);
    int*      row_ptr       = (int*)align(wp, (size_t)(N + 1) * 4);
    int*      bsum          = (int*)align(wp, 256 * 4);
    int*      bpre          = (int*)align(wp, 256 * 4);
    int*      bucket_cursor = (int*)align(wp, 256 * 4);
    unsigned* edges         = (unsigned*)align(wp, (size_t)E * 4);
    uint2*    part          = (uint2*)align(wp, (size_t)E * 8);

    const int eb = (E + 255) / 256;
    const int nb = (N + 255) / 256;   // 196 <= 256 (bucket = dst >> 8)

    hipMemsetAsync(counts, 0, (size_t)N * 4, stream);
    const int NX8 = N * 128 / 8;       // 800000
    {
        long long total = (long long)E + NX8 + 229376;
        int blocks = (int)((total + 255) / 256);
        prep_all<<<blocks, 256, 0, stream>>>(
            ei, counts, E, x, xb, xb8, NX8,
            w1_rel, w1_root, w2_rel, w2_root, w_lin,
            w1relT, w1rootT, w2relT, w2rootT, wlinT);
    }
    scan_block_sums<<<nb, 256, 0, stream>>>(counts, bsum, N);
    scan_bsum<<<1, 256, 0, stream>>>(bsum, bpre, bucket_cursor, nb);
    scan_final<<<nb, 256, 0, stream>>>(counts, bpre, row_ptr, N, E);
    // 2-pass bucket-partitioned fill
    {
        int p1_blocks = (E + 256 * P1_EPB - 1) / (256 * P1_EPB);   // 391
        part_kernel<<<p1_blocks, 256, 0, stream>>>(ei, ew, bucket_cursor, part, E);
        fill2_kernel<<<nb, 256, 0, stream>>>(part, bpre, bsum, row_ptr, edges, N);
    }

    const int gather_blocks = (N * 64 + 255) / 256;
    const int gemm_grid     = ((N + 127) / 128) * 2;
    const int head_grid     = (N + 127) / 128;

    // layer 1
    gather_fp8<128><<<gather_blocks, 256, 0, stream>>>(
        xb8, edges, row_ptr, agg1b, N);
    gemm_mfma<true><<<gemm_grid, 256, 0, stream>>>(
        agg1b, xb, w1relT, w1rootT, b1, x1b, x1b8, N, 128, 128);
    // layer 2
    gather_fp8<256><<<gather_blocks, 256, 0, stream>>>(
        x1b8, edges, row_ptr, agg2b, N);
    gemm_mfma<false><<<gemm_grid, 256, 0, stream>>>(
        agg2b, x1b, w2relT, w2rootT, b2, x2b, nullptr, N, 256, 256);
    // head
    head_mfma<<<head_grid, 256, 0, stream>>>(x1b, x2b, wlinT, b_lin, out, N);
}

// Round 13
// 181.792 us; speedup vs baseline: 1.4999x; 1.1443x over previous
//
#include <hip/hip_runtime.h>
#include <hip/hip_bf16.h>
#include <hip/hip_fp16.h>
#include <math.h>

// ---------------------------------------------------------------------------
// GraphConv GNN, round 12: per-node count scatter eliminated. Bucket-level
// histogram (LDS-aggregated, 38k atomics) + per-bucket CSR build inside
// fill2 (L2-local). prep_all is now pure streaming conversion.
// ---------------------------------------------------------------------------

typedef __attribute__((ext_vector_type(8))) short short8;
typedef __attribute__((ext_vector_type(4))) float f32x4;

static __device__ __forceinline__ float bf2f(unsigned short u) {
    return __uint_as_float(((unsigned)u) << 16);
}

// ---- fp8 e4m3 helpers -----------------------------------------------------
static __device__ __forceinline__ void fp8x4_to_f32(unsigned u, float* o) {
#if __has_builtin(__builtin_amdgcn_cvt_pk_f32_fp8)
    auto lo = __builtin_amdgcn_cvt_pk_f32_fp8((int)u, false);
    auto hi = __builtin_amdgcn_cvt_pk_f32_fp8((int)u, true);
    o[0] = lo[0]; o[1] = lo[1]; o[2] = hi[0]; o[3] = hi[1];
#else
#pragma unroll
    for (int i = 0; i < 4; ++i) {
        unsigned b = (u >> (8 * i)) & 0xffu;
        unsigned short hb = (unsigned short)(((b & 0x80u) << 8) | ((b & 0x7fu) << 7));
        o[i] = __half2float(__ushort_as_half(hb)) * 256.0f;
    }
#endif
}

static __device__ __forceinline__ unsigned f32_to_fp8(float f) {
    __half h = __float2half(f * 0.00390625f);            // 2^-8
    unsigned short hb = __half_as_ushort(h);
    unsigned mag = hb & 0x7fffu;
    unsigned s = (hb >> 8) & 0x80u;
    unsigned v = (mag + 0x3fu + ((mag >> 7) & 1u)) >> 7; // RNE
    if (v > 0x7eu) v = 0x7eu;                            // clamp below NaN
    return s | v;
}

// ---- bucket histogram: bhist[b] = #edges with dst>>8 == b -----------------
#define BH_EPB 16
__global__ __launch_bounds__(256) void bucket_hist(
    const int* __restrict__ ei, int* __restrict__ bhist, int E)
{
    __shared__ int lh[256];
    const int t = threadIdx.x;
    lh[t] = 0;
    __syncthreads();
    const int base = blockIdx.x * (256 * BH_EPB);
#pragma unroll
    for (int i = 0; i < BH_EPB; ++i) {
        int e = base + i * 256 + t;
        if (e < E) atomicAdd(&lh[ei[E + e] >> 8], 1);
    }
    __syncthreads();
    if (lh[t] > 0) atomicAdd(&bhist[t], lh[t]);
}

// ---- scan of bucket sums -> exclusive bases + reservation cursors ---------
__global__ __launch_bounds__(256) void scan_bsum(
    const int* __restrict__ bhist, int* __restrict__ bpre,
    int* __restrict__ bucket_cursor, int nb)
{
    __shared__ int sh[256];
    int t = threadIdx.x;
    int v = (t < nb) ? bhist[t] : 0;
    sh[t] = v;
    __syncthreads();
#pragma unroll
    for (int off = 1; off < 256; off <<= 1) {
        int u = (t >= off) ? sh[t - off] : 0;
        __syncthreads();
        sh[t] += u;
        __syncthreads();
    }
    bpre[t]          = sh[t] - v;   // exclusive
    bucket_cursor[t] = sh[t] - v;
}

// ---- fill pass 1: partition edges into 256-node buckets -------------------
#define P1_EPB 8
__global__ __launch_bounds__(256) void part_kernel(
    const int* __restrict__ ei, const float* __restrict__ ew,
    int* __restrict__ bucket_cursor, uint2* __restrict__ part, int E)
{
    __shared__ int lhist[256];
    __shared__ int gbase[256];
    const int t = threadIdx.x;
    const int base = blockIdx.x * (256 * P1_EPB);
    lhist[t] = 0;
    __syncthreads();

    int pk[P1_EPB];                     // (bucket<<16) | local_rank, -1 = none
#pragma unroll
    for (int i = 0; i < P1_EPB; ++i) {
        int e = base + i * 256 + t;
        if (e < E) {
            int b = ei[E + e] >> 8;
            int r = atomicAdd(&lhist[b], 1);
            pk[i] = (b << 16) | r;
        } else pk[i] = -1;
    }
    __syncthreads();
    if (lhist[t] > 0) gbase[t] = atomicAdd(&bucket_cursor[t], lhist[t]);
    __syncthreads();
#pragma unroll
    for (int i = 0; i < P1_EPB; ++i) {
        if (pk[i] >= 0) {
            int e = base + i * 256 + t;
            int d = ei[E + e];                       // L2-hot re-read
            unsigned short w16 = __half_as_ushort(__float2half(ew[e]));
            unsigned rec = ((unsigned)w16 << 16) | (unsigned)ei[e];
            int pos = gbase[pk[i] >> 16] + (pk[i] & 0xffff);
            part[pos] = make_uint2(rec, (unsigned)d);
        }
    }
}

// ---- fill pass 2: per-bucket CSR build + local scatter --------------------
// Builds row_ptr for its 256 nodes from its own L2-local part segment, then
// scatters edge records into the bucket's contiguous region.
__global__ __launch_bounds__(256) void fill2_kernel(
    const uint2* __restrict__ part, const int* __restrict__ bpre,
    const int* __restrict__ bhist, int* __restrict__ row_ptr,
    unsigned* __restrict__ edges, int n)
{
    __shared__ int lcnt[256];
    __shared__ int excl[256];
    __shared__ int curs[256];
    const int b = blockIdx.x;
    const int t = threadIdx.x;
    const int node0 = b << 8;
    lcnt[t] = 0;
    __syncthreads();
    const int beg = bpre[b];
    const int end = beg + bhist[b];
    for (int i = beg + t; i < end; i += 256)
        atomicAdd(&lcnt[part[i].y & 255u], 1);
    __syncthreads();
    // exclusive scan of per-node counts
    int v = lcnt[t];
    excl[t] = v;
    __syncthreads();
#pragma unroll
    for (int off = 1; off < 256; off <<= 1) {
        int u = (t >= off) ? excl[t - off] : 0;
        __syncthreads();
        excl[t] += u;
        __syncthreads();
    }
    const int base_t = beg + excl[t] - v;   // this node's CSR base
    const int nd = node0 + t;
    if (nd <= n) row_ptr[nd] = base_t;      // last bucket's nd==n slot -> E
    curs[t] = base_t;
    __syncthreads();
    for (int i = beg + t; i < end; i += 256) {
        uint2 p = part[i];
        int slot = atomicAdd(&curs[p.y & 255u], 1);
        edges[slot] = p.x;
    }
}

// ---- streaming prep: x->bf16+fp8 + weight transposes (no atomics) ---------
__global__ __launch_bounds__(256) void prep_all(
    const float* __restrict__ x, __hip_bfloat16* __restrict__ xb,
    unsigned char* __restrict__ xb8, int NX8,
    const float* __restrict__ w1_rel, const float* __restrict__ w1_root,
    const float* __restrict__ w2_rel, const float* __restrict__ w2_root,
    const float* __restrict__ w_lin,
    __hip_bfloat16* __restrict__ w1relT, __hip_bfloat16* __restrict__ w1rootT,
    __hip_bfloat16* __restrict__ w2relT, __hip_bfloat16* __restrict__ w2rootT,
    __hip_bfloat16* __restrict__ wlinT)
{
    int idx = blockIdx.x * 256 + threadIdx.x;
    if (idx < NX8) {   // x -> bf16 + fp8, 8 elems/thread
        float4 a = *(const float4*)&x[(size_t)idx * 8];
        float4 b = *(const float4*)&x[(size_t)idx * 8 + 4];
        float f[8] = { a.x, a.y, a.z, a.w, b.x, b.y, b.z, b.w };
        __hip_bfloat16 o[8];
#pragma unroll
        for (int i = 0; i < 8; ++i) o[i] = __float2bfloat16(f[i]);
        *(short8*)&xb[(size_t)idx * 8] = *(short8*)o;
        unsigned p0 = 0, p1 = 0;
#pragma unroll
        for (int i = 0; i < 4; ++i) p0 |= f32_to_fp8(f[i]) << (8 * i);
#pragma unroll
        for (int i = 0; i < 4; ++i) p1 |= f32_to_fp8(f[4 + i]) << (8 * i);
        *(uint2*)&xb8[(size_t)idx * 8] = make_uint2(p0, p1);
        return;
    }
    idx -= NX8;
    if (idx < 65536) {                       // w1_rel/w1_root [128,256] -> [256,128]
        const float* src = (idx < 32768) ? w1_rel : w1_root;
        __hip_bfloat16* dst = (idx < 32768) ? w1relT : w1rootT;
        int i = idx & 32767;
        int k = i >> 8, c = i & 255;
        dst[c * 128 + k] = __float2bfloat16(src[i]);
    } else if (idx < 196608) {               // w2_rel/w2_root [256,256]^T
        int j = idx - 65536;
        const float* src = (j < 65536) ? w2_rel : w2_root;
        __hip_bfloat16* dst = (j < 65536) ? w2relT : w2rootT;
        int i = j & 65535;
        int k = i >> 8, c = i & 255;
        dst[c * 256 + k] = __float2bfloat16(src[i]);
    } else if (idx < 229376) {               // w_lin [512,40] -> [2][64][256]
        int i = idx - 196608;
        int seg = i >> 14, c = (i >> 8) & 63, k = i & 255;
        float v = (c < 40) ? w_lin[(size_t)(seg * 256 + k) * 40 + c] : 0.f;
        wlinT[i] = __float2bfloat16(v);
    }
}

// ---- gather (fp8 table, 4B edges): agg[v,:] = sum_e w_e * feat8[src_e,:] --
template <int C>
__global__ __launch_bounds__(256) void gather_fp8(
    const unsigned char* __restrict__ feat8,
    const unsigned* __restrict__ edges,
    const int*  __restrict__ rp,
    __hip_bfloat16* __restrict__ agg, int n)
{
    const int node = (blockIdx.x * 256 + threadIdx.x) >> 6;
    const int lane = threadIdx.x & 63;
    if (node >= n) return;
    const int beg = __builtin_amdgcn_readfirstlane(rp[node]);
    const int end = __builtin_amdgcn_readfirstlane(rp[node + 1]);

    constexpr int EPW = (C == 128) ? 8 : 4;       // edge slots per step
    constexpr int LPR = 64 / EPW;                 // lanes per row
    const int es = lane / LPR;
    const int ch = lane % LPR;
    const unsigned coff = (unsigned)ch * 16;      // byte offset of 16-elem chunk

    float acc[16] = {};

    auto accum16 = [&](uint4 u, float w) {
        unsigned uu[4] = { u.x, u.y, u.z, u.w };
#pragma unroll
        for (int q = 0; q < 4; ++q) {
            float f[4];
            fp8x4_to_f32(uu[q], f);
#pragma unroll
            for (int i = 0; i < 4; ++i)
                acc[q * 4 + i] = fmaf(f[i], w, acc[q * 4 + i]);
        }
    };

    auto unpack_w = [](unsigned p) {
        return __half2float(__ushort_as_half((unsigned short)(p >> 16)));
    };

    for (int base = beg; base < end; base += 64) {
        const int m = min(64, end - base);
        unsigned ev = edges[base + ((lane < m) ? lane : (m - 1))];
        if (lane >= m) ev &= 0xffffu;     // zero the weight half (shfl-safe)

        int s = 0;
        for (; s + 2 * EPW <= m; s += 2 * EPW) {
            int j0 = s + es, j1 = j0 + EPW;
            unsigned p0 = (unsigned)__shfl((int)ev, j0, 64);
            unsigned p1 = (unsigned)__shfl((int)ev, j1, 64);
            uint4 u0 = *(const uint4*)(feat8 + (size_t)(p0 & 0xffffu) * C + coff);
            uint4 u1 = *(const uint4*)(feat8 + (size_t)(p1 & 0xffffu) * C + coff);
            accum16(u0, unpack_w(p0));
            accum16(u1, unpack_w(p1));
        }
        for (; s < m; s += EPW) {
            int j = min(s + es, 63);
            unsigned p = (unsigned)__shfl((int)ev, j, 64);
            uint4 u = *(const uint4*)(feat8 + (size_t)(p & 0xffffu) * C + coff);
            accum16(u, unpack_w(p));
        }
    }

#pragma unroll
    for (int k = 0; k < 16; ++k) {
        if constexpr (C == 128) {
            acc[k] += __shfl_xor(acc[k], 8, 64);
            acc[k] += __shfl_xor(acc[k], 16, 64);
            acc[k] += __shfl_xor(acc[k], 32, 64);
        } else {
            acc[k] += __shfl_xor(acc[k], 16, 64);
            acc[k] += __shfl_xor(acc[k], 32, 64);
        }
    }
    if (es == 0) {
        __hip_bfloat16 o[16];
#pragma unroll
        for (int k = 0; k < 16; ++k) o[k] = __float2bfloat16(acc[k]);
        __hip_bfloat16* op = agg + (size_t)node * C + ch * 16;
        *(short8*)op       = *(short8*)o;
        *(short8*)(op + 8) = *(short8*)(o + 8);
    }
}

// ---- MFMA GEMM: C = relu(A0@W0 + A1@W1 + bias), NC=256, bf16 in/out -------
template <bool WRITE_FP8>
__global__ __launch_bounds__(256) void gemm_mfma(
    const __hip_bfloat16* __restrict__ A0, const __hip_bfloat16* __restrict__ A1,
    const __hip_bfloat16* __restrict__ W0T, const __hip_bfloat16* __restrict__ W1T,
    const float* __restrict__ bias,
    __hip_bfloat16* __restrict__ Cmat,
    unsigned char* __restrict__ Cfp8,
    int n, int K0, int K1)
{
    __shared__ __hip_bfloat16 Asl[2][128 * 64];   // 32 KB
    __shared__ __hip_bfloat16 Bsl[2][128 * 64];   // 32 KB
    const int bm = blockIdx.x >> 1;
    const int bn = blockIdx.x & 1;
    const int row0 = bm * 128, col0 = bn * 128;
    const int t = threadIdx.x, lane = t & 63, wid = t >> 6;
    const int wr = wid >> 1, wc = wid & 1;

    const int S0 = K0 >> 6;
    const int S  = S0 + (K1 >> 6);

    auto stage = [&](int buf, int s) {
        const __hip_bfloat16* A;
        const __hip_bfloat16* WT;
        int K, k0;
        if (s < S0) { A = A0; WT = W0T; K = K0; k0 = s << 6; }
        else        { A = A1; WT = W1T; K = K1; k0 = (s - S0) << 6; }
#pragma unroll
        for (int i = 0; i < 4; ++i) {
            int idx = i * 256 + t;
            int r = idx >> 3, c = idx & 7;
            int gr = row0 + r; if (gr >= n) gr = n - 1;
            const __hip_bfloat16* srcA =
                A + (size_t)gr * K + k0 + ((c ^ (r & 7)) << 3);
            __builtin_amdgcn_global_load_lds(
                (const __attribute__((address_space(1))) void*)srcA,
                (__attribute__((address_space(3))) void*)&Asl[buf][idx * 8], 16, 0, 0);
            const __hip_bfloat16* srcB =
                WT + (size_t)(col0 + r) * K + k0 + ((c ^ (r & 7)) << 3);
            __builtin_amdgcn_global_load_lds(
                (const __attribute__((address_space(1))) void*)srcB,
                (__attribute__((address_space(3))) void*)&Bsl[buf][idx * 8], 16, 0, 0);
        }
    };

    f32x4 acc[4][4] = {};

    stage(0, 0);
    __syncthreads();

    for (int s = 0; s < S; ++s) {
        const int buf = s & 1;
        if (s + 1 < S) stage(buf ^ 1, s + 1);
#pragma unroll
        for (int kh = 0; kh < 2; ++kh) {
            const int cchunk = kh * 4 + (lane >> 4);
            short8 af[4], bfr[4];
#pragma unroll
            for (int m = 0; m < 4; ++m) {
                int r = wr * 64 + m * 16 + (lane & 15);
                af[m] = *(const short8*)&Asl[buf][r * 64 + ((cchunk ^ (r & 7)) << 3)];
            }
#pragma unroll
            for (int nn = 0; nn < 4; ++nn) {
                int r = wc * 64 + nn * 16 + (lane & 15);
                bfr[nn] = *(const short8*)&Bsl[buf][r * 64 + ((cchunk ^ (r & 7)) << 3)];
            }
#pragma unroll
            for (int m = 0; m < 4; ++m)
#pragma unroll
                for (int nn = 0; nn < 4; ++nn)
                    acc[m][nn] = __builtin_amdgcn_mfma_f32_16x16x32_bf16(
                        af[m], bfr[nn], acc[m][nn], 0, 0, 0);
        }
        __syncthreads();
    }

    // epilogue: bias+relu -> LDS tile -> coalesced global writes
    __hip_bfloat16* Csh = &Asl[0][0];
#pragma unroll
    for (int nn = 0; nn < 4; ++nn) {
        int lcol = wc * 64 + nn * 16 + (lane & 15);
        float b = bias[col0 + lcol];
#pragma unroll
        for (int m = 0; m < 4; ++m) {
#pragma unroll
            for (int rg = 0; rg < 4; ++rg) {
                int lrow = wr * 64 + m * 16 + ((lane >> 4) * 4) + rg;
                float v = fmaxf(acc[m][nn][rg] + b, 0.f);
                Csh[lrow * 128 + lcol] = __float2bfloat16(v);
            }
        }
    }
    __syncthreads();

#pragma unroll
    for (int it = 0; it < 8; ++it) {
        int idx = it * 256 + t;
        int r = idx >> 4, c16 = idx & 15;
        if (row0 + r < n)
            *(short8*)(Cmat + (size_t)(row0 + r) * 256 + col0 + c16 * 8) =
                *(const short8*)&Csh[r * 128 + c16 * 8];
    }
    if constexpr (WRITE_FP8) {
#pragma unroll
        for (int it = 0; it < 4; ++it) {
            int idx = it * 256 + t;
            int r = idx >> 3, c16 = idx & 7;
            if (row0 + r < n) {
                const __hip_bfloat16* src = &Csh[r * 128 + c16 * 16];
                unsigned w[4];
#pragma unroll
                for (int q = 0; q < 4; ++q) {
                    unsigned p = 0;
#pragma unroll
                    for (int i = 0; i < 4; ++i)
                        p |= f32_to_fp8(__bfloat162float(src[q * 4 + i])) << (8 * i);
                    w[q] = p;
                }
                *(uint4*)(Cfp8 + (size_t)(row0 + r) * 256 + col0 + c16 * 16) =
                    make_uint4(w[0], w[1], w[2], w[3]);
            }
        }
    }
}

// ---- head: out = log_softmax([x1|x2] @ w_lin + b_lin), MFMA fused ---------
__global__ __launch_bounds__(256) void head_mfma(
    const __hip_bfloat16* __restrict__ X1, const __hip_bfloat16* __restrict__ X2,
    const __hip_bfloat16* __restrict__ WLT,   // [2][64][256]
    const float* __restrict__ b_lin,
    float* __restrict__ out, int n)
{
    __shared__ __hip_bfloat16 Asl[128 * 64];
    __shared__ __hip_bfloat16 Bsl[64 * 64];
    const int row0 = blockIdx.x * 128;
    const int t = threadIdx.x, lane = t & 63, wid = t >> 6;

    f32x4 acc[2][4] = {};

    for (int seg = 0; seg < 2; ++seg) {
        const __hip_bfloat16* A  = seg ? X2 : X1;
        const __hip_bfloat16* WT = WLT + seg * 64 * 256;
        for (int k0 = 0; k0 < 256; k0 += 64) {
#pragma unroll
            for (int i = 0; i < 4; ++i) {
                int idx = i * 256 + t;
                int r = idx >> 3, c = idx & 7;
                int gr = row0 + r; if (gr >= n) gr = n - 1;
                const __hip_bfloat16* srcA =
                    A + (size_t)gr * 256 + k0 + ((c ^ (r & 7)) << 3);
                __builtin_amdgcn_global_load_lds(
                    (const __attribute__((address_space(1))) void*)srcA,
                    (__attribute__((address_space(3))) void*)&Asl[idx * 8], 16, 0, 0);
            }
#pragma unroll
            for (int i = 0; i < 2; ++i) {
                int idx = i * 256 + t;
                int r = idx >> 3, c = idx & 7;
                const __hip_bfloat16* srcB =
                    WT + (size_t)r * 256 + k0 + ((c ^ (r & 7)) << 3);
                __builtin_amdgcn_global_load_lds(
                    (const __attribute__((address_space(1))) void*)srcB,
                    (__attribute__((address_space(3))) void*)&Bsl[idx * 8], 16, 0, 0);
            }
            __syncthreads();
#pragma unroll
            for (int kh = 0; kh < 2; ++kh) {
                const int cchunk = kh * 4 + (lane >> 4);
                short8 af[2], bfr[4];
#pragma unroll
                for (int m = 0; m < 2; ++m) {
                    int r = wid * 32 + m * 16 + (lane & 15);
                    af[m] = *(const short8*)&Asl[r * 64 + ((cchunk ^ (r & 7)) << 3)];
                }
#pragma unroll
                for (int nn = 0; nn < 4; ++nn) {
                    int r = nn * 16 + (lane & 15);
                    bfr[nn] = *(const short8*)&Bsl[r * 64 + ((cchunk ^ (r & 7)) << 3)];
                }
#pragma unroll
                for (int m = 0; m < 2; ++m)
#pragma unroll
                    for (int nn = 0; nn < 4; ++nn)
                        acc[m][nn] = __builtin_amdgcn_mfma_f32_16x16x32_bf16(
                            af[m], bfr[nn], acc[m][nn], 0, 0, 0);
            }
            __syncthreads();
        }
    }

    const int cl = lane & 15;
    float bb[4];
#pragma unroll
    for (int nn = 0; nn < 4; ++nn) {
        int col = nn * 16 + cl;
        bb[nn] = (col < 40) ? b_lin[col] : 0.f;
    }
#pragma unroll
    for (int m = 0; m < 2; ++m) {
#pragma unroll
        for (int rg = 0; rg < 4; ++rg) {
            float v[4];
            float mx = -1e30f;
#pragma unroll
            for (int nn = 0; nn < 4; ++nn) {
                int col = nn * 16 + cl;
                v[nn] = acc[m][nn][rg] + bb[nn];
                if (col < 40) mx = fmaxf(mx, v[nn]);
            }
#pragma unroll
            for (int off = 1; off < 16; off <<= 1)
                mx = fmaxf(mx, __shfl_xor(mx, off, 64));
            float s = 0.f;
#pragma unroll
            for (int nn = 0; nn < 4; ++nn) {
                int col = nn * 16 + cl;
                if (col < 40) s += expf(v[nn] - mx);
            }
#pragma unroll
            for (int off = 1; off < 16; off <<= 1)
                s += __shfl_xor(s, off, 64);
            float ls = logf(s);
            int row = row0 + wid * 32 + m * 16 + ((lane >> 4) * 4) + rg;
            if (row < n) {
#pragma unroll
                for (int nn = 0; nn < 4; ++nn) {
                    int col = nn * 16 + cl;
                    if (col < 40)
                        out[(size_t)row * 40 + col] = v[nn] - mx - ls;
                }
            }
        }
    }
}

// ---------------------------------------------------------------------------
extern "C" void kernel_launch(void* const* d_in, const int* in_sizes, int n_in,
                              void* d_out, int out_size, void* d_ws, size_t ws_size,
                              hipStream_t stream)
{
    const float* x       = (const float*)d_in[0];
    const int*   ei      = (const int*)  d_in[1];
    const float* ew      = (const float*)d_in[2];
    const float* w1_rel  = (const float*)d_in[3];
    const float* b1      = (const float*)d_in[4];
    const float* w1_root = (const float*)d_in[5];
    const float* w2_rel  = (const float*)d_in[6];
    const float* b2      = (const float*)d_in[7];
    const float* w2_root = (const float*)d_in[8];
    const float* w_lin   = (const float*)d_in[9];
    const float* b_lin   = (const float*)d_in[10];
    float* out = (float*)d_out;

    const int N = in_sizes[0] / 128;   // 50000 (< 65536: u16 src pack valid)
    const int E = in_sizes[2];         // 800000

    auto align = [](char*& p, size_t bytes) {
        char* r = p;
        p += (bytes + 255) & ~(size_t)255;
        return r;
    };
    char* wp = (char*)d_ws;
    __hip_bfloat16* xb     = (__hip_bfloat16*)align(wp, (size_t)N * 128 * 2);
    __hip_bfloat16* agg1b  = (__hip_bfloat16*)align(wp, (size_t)N * 128 * 2);
    __hip_bfloat16* x1b    = (__hip_bfloat16*)align(wp, (size_t)N * 256 * 2);
    __hip_bfloat16* agg2b  = (__hip_bfloat16*)align(wp, (size_t)N * 256 * 2);
    __hip_bfloat16* x2b    = (__hip_bfloat16*)align(wp, (size_t)N * 256 * 2);
    unsigned char*  xb8    = (unsigned char*)align(wp, (size_t)N * 128);
    unsigned char*  x1b8   = (unsigned char*)align(wp, (size_t)N * 256);
    __hip_bfloat16* w1relT  = (__hip_bfloat16*)align(wp, 256 * 128 * 2);
    __hip_bfloat16* w1rootT = (__hip_bfloat16*)align(wp, 256 * 128 * 2);
    __hip_bfloat16* w2relT  = (__hip_bfloat16*)align(wp, 256 * 256 * 2);
    __hip_bfloat16* w2rootT = (__hip_bfloat16*)align(wp, 256 * 256 * 2);
    __hip_bfloat16* wlinT   = (__hip_bfloat16*)align(wp, 2 * 64 * 256 * 2);
    int*      row_ptr       = (int*)align(wp, (size_t)(N + 1) * 4);
    int*      bhist         = (int*)align(wp, 256 * 4);
    int*      bpre          = (int*)align(wp, 256 * 4);
    int*      bucket_cursor = (int*)align(wp, 256 * 4);
    unsigned* edges         = (unsigned*)align(wp, (size_t)E * 4);
    uint2*    part          = (uint2*)align(wp, (size_t)E * 8);

    const int nb = (N + 255) / 256;   // 196 buckets (bucket = dst >> 8)

    hipMemsetAsync(bhist, 0, 256 * 4, stream);
    const int NX8 = N * 128 / 8;       // 800000
    {
        long long total = (long long)NX8 + 229376;
        int blocks = (int)((total + 255) / 256);
        prep_all<<<blocks, 256, 0, stream>>>(
            x, xb, xb8, NX8,
            w1_rel, w1_root, w2_rel, w2_root, w_lin,
            w1relT, w1rootT, w2relT, w2rootT, wlinT);
    }
    // CSR build: bucket histogram -> scan -> partition -> per-bucket CSR
    {
        int bh_blocks = (E + 256 * BH_EPB - 1) / (256 * BH_EPB);   // 196
        bucket_hist<<<bh_blocks, 256, 0, stream>>>(ei, bhist, E);
        scan_bsum<<<1, 256, 0, stream>>>(bhist, bpre, bucket_cursor, nb);
        int p1_blocks = (E + 256 * P1_EPB - 1) / (256 * P1_EPB);   // 391
        part_kernel<<<p1_blocks, 256, 0, stream>>>(ei, ew, bucket_cursor, part, E);
        fill2_kernel<<<nb, 256, 0, stream>>>(part, bpre, bhist, row_ptr, edges, N);
    }

    const int gather_blocks = (N * 64 + 255) / 256;
    const int gemm_grid     = ((N + 127) / 128) * 2;
    const int head_grid     = (N + 127) / 128;

    // layer 1
    gather_fp8<128><<<gather_blocks, 256, 0, stream>>>(
        xb8, edges, row_ptr, agg1b, N);
    gemm_mfma<true><<<gemm_grid, 256, 0, stream>>>(
        agg1b, xb, w1relT, w1rootT, b1, x1b, x1b8, N, 128, 128);
    // layer 2
    gather_fp8<256><<<gather_blocks, 256, 0, stream>>>(
        x1b8, edges, row_ptr, agg2b, N);
    gemm_mfma<false><<<gemm_grid, 256, 0, stream>>>(
        agg2b, x1b, w2relT, w2rootT, b2, x2b, nullptr, N, 256, 256);
    // head
    head_mfma<<<head_grid, 256, 0, stream>>>(x1b, x2b, wlinT, b_lin, out, N);
}